// Round 6
// baseline (1820.849 us; speedup 1.0000x reference)
//
#include <hip/hip_runtime.h>
#include <hip/hip_bf16.h>
#include <math.h>

#define NN   29040
#define NLAT 121
#define NLON 240
#define HD   128
#define LVN  11
#define EE   464640
#define NT   3630          // edge tiles (128 edges each)
#define EGRID 512          // edge kernel grid

typedef __attribute__((ext_vector_type(8))) short short8;
typedef __attribute__((ext_vector_type(4))) float f4;

// packed-weight offsets (in shorts) inside wp buffer
#define OFF_WE1 0          // 10 kf x 8 nf  = 80 frags
#define OFF_WE2 40960      // 4 x 8 = 32
#define OFF_WC1 57344      // 4 x 8 = 32
#define OFF_WCL 73728      // 4 x 2 = 8
#define OFF_WN1 77824      // 12 x 8 = 96
#define OFF_WN2 126976     // 4 x 8 = 32
#define WP_SHORTS 143360

__device__ inline short f2b(float x) {
    union { __hip_bfloat16 b; short s; } v;
    v.b = __float2bfloat16(x);
    return v.s;
}
__device__ inline float b2f(unsigned short b) {
    union { unsigned u; float f; } v; v.u = ((unsigned)b) << 16;
    return v.f;
}

// ================= fused setup: hist | h-cast | uv-prep | weight-pack =================
#define SB_HIST  1815
#define SB_HCAST 1815
#define SB_UV    114
#define SB_WP    70

__global__ __launch_bounds__(256)
void setup_kernel(const int* __restrict__ eidx, int* __restrict__ cnt,
                  const float* __restrict__ h, short* __restrict__ hb,
                  const float* __restrict__ u, const float* __restrict__ v,
                  float* __restrict__ uvrec,
                  const float* __restrict__ We1, const float* __restrict__ We2,
                  const float* __restrict__ Wc1, const float* __restrict__ Wcl,
                  const float* __restrict__ Wn1, const float* __restrict__ Wn2,
                  short* __restrict__ wp)
{
    const int b = blockIdx.x, tid = threadIdx.x;
    if (b < SB_HIST) {
        int e = b * 256 + tid;
        atomicAdd(&cnt[eidx[e]], 1);
        return;
    }
    if (b < SB_HIST + SB_HCAST) {
        int idx = (b - SB_HIST) * 256 + tid;          // 8 elems each
        const float4* hf = (const float4*)h;
        float4 a = hf[idx * 2], c = hf[idx * 2 + 1];
        short8 o;
        o[0] = f2b(a.x); o[1] = f2b(a.y); o[2] = f2b(a.z); o[3] = f2b(a.w);
        o[4] = f2b(c.x); o[5] = f2b(c.y); o[6] = f2b(c.z); o[7] = f2b(c.w);
        ((short8*)hb)[idx] = o;
        return;
    }
    if (b < SB_HIST + SB_HCAST + SB_UV) {
        int n = (b - SB_HIST - SB_HCAST) * 256 + tid;
        if (n >= NN) return;
        float* r = uvrec + (size_t)n * 36;
        float un = 0.f, vn = 0.f;
#pragma unroll
        for (int l = 0; l < LVN; ++l) {
            float uu = u[n * LVN + l], vv = v[n * LVN + l];
            float s = sqrtf(uu * uu + vv * vv);
            r[l]      = uu / s;
            r[11 + l] = vv / s;
            r[22 + l] = s;
            un += uu * uu; vn += vv * vv;
        }
        r[33] = sqrtf(un);
        r[34] = sqrtf(vn);
        r[35] = 0.f;
        return;
    }
    // weight pack: 4 fragments per block
    {
        int fg = (b - SB_HIST - SB_HCAST - SB_UV) * 4 + (tid >> 6);   // 0..279
        const int l = tid & 63;
        int kind, f, base;
        if (fg < 80)       { kind = 0; f = fg;       base = OFF_WE1; }
        else if (fg < 112) { kind = 1; f = fg - 80;  base = OFF_WE2; }
        else if (fg < 144) { kind = 2; f = fg - 112; base = OFF_WC1; }
        else if (fg < 152) { kind = 3; f = fg - 144; base = OFF_WCL; }
        else if (fg < 248) { kind = 4; f = fg - 152; base = OFF_WN1; }
        else               { kind = 5; f = fg - 248; base = OFF_WN2; }
        const int nfw = (kind == 3) ? 2 : 8;
        const int kf = f / nfw, nf = f % nfw;
        short* dst = wp + base + (size_t)f * 512 + l * 8;
        for (int i = 0; i < 8; ++i) {
            int k = kf * 32 + ((l >> 4) << 3) + i;
            int n = nf * 16 + (l & 15);
            float val = 0.f;
            if (kind == 0) {
                int r = (k < 33) ? (256 + k) : (k == 33 ? 289 : (k < 64 ? -1 : k - 64));
                if (r >= 0) val = We1[r * HD + n];
            } else if (kind == 1) val = We2[k * HD + n];
            else if (kind == 2)  val = Wc1[k * HD + n];
            else if (kind == 3)  { if (n < 22) val = Wcl[k * 22 + n]; }
            else if (kind == 4)  val = Wn1[k * HD + n];
            else                 val = Wn2[k * HD + n];
            dst[i] = f2b(val);
        }
    }
}

// ================= CSR scan + scatter =================
__global__ __launch_bounds__(1024)
void scan_kernel(const int* __restrict__ cnt, int* __restrict__ off)
{
    __shared__ int part[1024];
    const int tid = threadIdx.x;
    const int CH = 29;
    int lo = tid * CH, hi = min(lo + CH, NN);
    int s = 0;
    for (int i = lo; i < hi; ++i) s += cnt[i];
    part[tid] = s;
    __syncthreads();
    for (int d = 1; d < 1024; d <<= 1) {
        int vv = (tid >= d) ? part[tid - d] : 0;
        __syncthreads();
        part[tid] += vv;
        __syncthreads();
    }
    int run = (tid == 0) ? 0 : part[tid - 1];
    for (int i = lo; i < hi; ++i) { off[i] = run; run += cnt[i]; }
    if (tid == 1023) off[NN] = run;
}

__global__ __launch_bounds__(256)
void scatter_kernel(const int* __restrict__ eidx, const int* __restrict__ off,
                    int* __restrict__ cur, int* __restrict__ csr)
{
    int e = blockIdx.x * 256 + threadIdx.x;
    if (e >= EE) return;
    int row = eidx[e];
    int p = atomicAdd(&cur[row], 1);
    csr[off[row] + p] = e;
}

// ================= GEMM helpers =================
template<int KF, int NF>
__device__ inline void layer_gemm(const short* At, int rs, const short* Wp,
                                  const float* bias, f4* acc, int w, int lane)
{
    const int m = 16 * w + (lane & 15);
    const char* arow = (const char*)At + m * rs;
    const int sw = (m & 7) << 4;
    const int kb = (lane >> 4) << 4;
#pragma unroll
    for (int nf = 0; nf < NF; ++nf) {
        float bv = bias ? bias[nf * 16 + (lane & 15)] : 0.f;
        acc[nf] = (f4){bv, bv, bv, bv};
    }
#pragma unroll
    for (int kf = 0; kf < KF; ++kf) {
        short8 a = *(const short8*)(arow + ((kf * 64 + kb) ^ sw));
        const short8* wr = (const short8*)(Wp + (size_t)kf * NF * 512) + lane;
#pragma unroll
        for (int nf = 0; nf < NF; ++nf) {
            short8 bfr = wr[nf * 64];
            acc[nf] = __builtin_amdgcn_mfma_f32_16x16x32_bf16(a, bfr, acc[nf], 0, 0, 0);
        }
    }
}

template<int NF>
__device__ inline void store_tile(short* tile, int rs, const f4* acc, int w, int lane)
{
    const int rb = 16 * w + ((lane >> 4) << 2);
    const int cb = (lane & 15) * 2;
#pragma unroll
    for (int nf = 0; nf < NF; ++nf)
#pragma unroll
        for (int r = 0; r < 4; ++r) {
            int row = rb + r;
            float vv = fmaxf(acc[nf][r], 0.f);
            *(short*)((char*)tile + row * rs + ((cb + nf * 32) ^ ((row & 7) << 4))) = f2b(vv);
        }
}

// ================= edge kernel: pipelined grid-stride =================
// launch_bounds (512,2): 2 waves/EU floor => 256-VGPR budget. (512,4) made the
// allocator clamp to 64 VGPRs and spill the pipeline state to scratch (round 5:
// WRITE_SIZE 807 MB, 7x slowdown).
__global__ __launch_bounds__(512, 2)
void edge_mfma(const short* __restrict__ hb, const float* __restrict__ uvrec,
               const float* __restrict__ ea,
               const float* __restrict__ be1, const float* __restrict__ be2,
               const float* __restrict__ bc1,
               const short* __restrict__ wp,
               const int* __restrict__ eidx, const int* __restrict__ csr,
               float* __restrict__ agg, float* __restrict__ aggu,
               float* __restrict__ aggv)
{
    __shared__ short Twd[128 * 64];    // 16 KB wd tile (128B rows); later O22 f32
    __shared__ short T1[128 * 128];    // 32 KB (256B rows)
    __shared__ int   rows_s[128];
    __shared__ float radu_s[128], radv_s[128];

    const int tid = threadIdx.x, lane = tid & 63, w = tid >> 6;
    const int mrow = 16 * w + (lane & 15);
    const int koff = 8 * (lane >> 4);
    const int sw   = (mrow & 7) << 4;
    const int m2 = tid >> 2, q = tid & 3;
    const int sw2 = (m2 & 7) << 4;

    // ---- prologue prefetch for first tile ----
    int t = blockIdx.x;
    int e1 = csr[t * 128 + mrow];
    int e2 = csr[t * 128 + m2];
    int rowm = eidx[e1], colm = eidx[EE + e1];
    int row2 = eidx[e2], col2 = eidx[EE + e2];
    float ean = ea[e2];
    short8 acp[4];
    {
        const short* hc = hb + (size_t)colm * HD + koff;
#pragma unroll
        for (int kf = 0; kf < 4; ++kf) acp[kf] = *(const short8*)(hc + kf * 32);
    }

    for (; t < NT; t += EGRID) {
        // ==== commit: uvrec loads (col random, row cached), Twd build, rows_s ====
        {
            const float* rc = uvrec + (size_t)col2 * 36;
            const float* rr = uvrec + (size_t)row2 * 36;
            char* arow = (char*)(Twd + m2 * 64);
            short8 z = {0, 0, 0, 0, 0, 0, 0, 0};
            *(short8*)(arow + q * 32) = z;
            *(short8*)(arow + q * 32 + 16) = z;
            for (int l = q; l < LVN; l += 4) {
                float rel = rc[l] * rr[l] + rc[11 + l] * rr[11 + l];
                *(short*)(arow + ((2 * l) ^ sw2))        = f2b(rel);
                *(short*)(arow + ((2 * (11 + l)) ^ sw2)) = f2b(rc[22 + l]);
                *(short*)(arow + ((2 * (22 + l)) ^ sw2)) = f2b(rr[22 + l]);
            }
            if (q == 0) { rows_s[m2] = row2; radu_s[m2] = rc[33]; radv_s[m2] = rc[34]; }
            if (q == 3) *(short*)(arow + ((2 * 33) ^ sw2)) = f2b(ean);
        }
        __syncthreads();   // B1: Twd/rows_s/rad visible

        // --- prefetch stage 1: csr for next tile ---
        int tn = t + EGRID; if (tn >= NT) tn = t;
        int e1n = csr[tn * 128 + mrow];
        int e2n = csr[tn * 128 + m2];

        // ==== edge MLP layer 1 ====
        f4 acc[8];
#pragma unroll
        for (int nf = 0; nf < 8; ++nf) {
            float bv = be1[nf * 16 + (lane & 15)];
            acc[nf] = (f4){bv, bv, bv, bv};
        }
        {
            const char* awd = (const char*)(Twd + mrow * 64);
#pragma unroll
            for (int kf = 0; kf < 2; ++kf) {
                short8 a = *(const short8*)(awd + ((kf * 64 + 2 * koff) ^ sw));
                const short8* wr = (const short8*)(wp + OFF_WE1 + (size_t)kf * 8 * 512) + lane;
#pragma unroll
                for (int nf = 0; nf < 8; ++nf)
                    acc[nf] = __builtin_amdgcn_mfma_f32_16x16x32_bf16(a, wr[nf * 64], acc[nf], 0, 0, 0);
            }
            const short* hr = hb + (size_t)rowm * HD + koff;   // CSR-local, L1-hot
#pragma unroll
            for (int kf = 0; kf < 4; ++kf) {
                short8 a = *(const short8*)(hr + kf * 32);
                const short8* wr = (const short8*)(wp + OFF_WE1 + (size_t)(kf + 2) * 8 * 512) + lane;
#pragma unroll
                for (int nf = 0; nf < 8; ++nf)
                    acc[nf] = __builtin_amdgcn_mfma_f32_16x16x32_bf16(a, wr[nf * 64], acc[nf], 0, 0, 0);
            }
#pragma unroll
            for (int kf = 0; kf < 4; ++kf) {
                const short8* wr = (const short8*)(wp + OFF_WE1 + (size_t)(kf + 6) * 8 * 512) + lane;
#pragma unroll
                for (int nf = 0; nf < 8; ++nf)
                    acc[nf] = __builtin_amdgcn_mfma_f32_16x16x32_bf16(acp[kf], wr[nf * 64], acc[nf], 0, 0, 0);
            }
        }
        store_tile<8>(T1, 256, acc, w, lane);     // Y1 (wave-private rows)

        // --- prefetch stage 2: eidx/ea for next tile ---
        int rowmn = eidx[e1n], colmn = eidx[EE + e1n];
        int row2n = eidx[e2n], col2n = eidx[EE + e2n];
        float eann = ea[e2n];

        // ==== edge MLP layer 2 -> EF (wave-private) ====
        layer_gemm<4, 8>(T1, 256, wp + OFF_WE2, be2, acc, w, lane);
        store_tile<8>(T1, 256, acc, w, lane);

        // ==== coord MLP layer 1 (wave-private EF) ====
        f4 accC[8];
        layer_gemm<4, 8>(T1, 256, wp + OFF_WC1, bc1, accC, w, lane);

        // --- prefetch stage 3: random h[col] fragments for next tile ---
        short8 acn[4];
        {
            const short* hc = hb + (size_t)colmn * HD + koff;
#pragma unroll
            for (int kf = 0; kf < 4; ++kf) acn[kf] = *(const short8*)(hc + kf * 32);
        }

        __syncthreads();   // B2: EF tile complete
        // ==== agg: segmented reduce over sorted rows ====
        {
            const int n = tid & 127, qq = tid >> 7;
            const int m0 = qq * 32;
            int curr = rows_s[m0]; float s = 0.f;
            for (int m = m0; m < m0 + 32; ++m) {
                int r = rows_s[m];
                float vv = b2f(*(const unsigned short*)((const char*)(T1 + m * 128) + ((2 * n) ^ ((m & 7) << 4))));
                if (r != curr) { atomicAdd(&agg[(size_t)curr * HD + n], s); s = 0.f; curr = r; }
                s += vv;
            }
            atomicAdd(&agg[(size_t)curr * HD + n], s);
        }
        __syncthreads();   // B3: EF reads done, T1 reusable

        // ==== coord C1 -> T1, final CL layer, O22 ====
        store_tile<8>(T1, 256, accC, w, lane);
        layer_gemm<4, 2>(T1, 256, wp + OFF_WCL, (const float*)nullptr, accC, w, lane);
        float* O22 = (float*)Twd;
        {
            const int rb = 16 * w + ((lane >> 4) << 2), cb = lane & 15;
#pragma unroll
            for (int nf = 0; nf < 2; ++nf)
#pragma unroll
                for (int r = 0; r < 4; ++r)
                    O22[(rb + r) * 32 + nf * 16 + cb] = accC[nf][r];
        }
        __syncthreads();   // B4: O22 visible

        // ==== wind: segmented reduce ====
        if (tid < 256) {
            const int c = tid & 31, qq = tid >> 5;
            if (c < 22) {
                const bool isU = c < LVN;
                const int lvl = isU ? c : c - LVN;
                float* dst = isU ? aggu : aggv;
                const float* radp = isU ? radu_s : radv_s;
                const int m0 = qq * 16;
                int curr = rows_s[m0]; float s = 0.f;
                for (int m = m0; m < m0 + 16; ++m) {
                    int r = rows_s[m];
                    float vv = O22[m * 32 + c] * radp[m];
                    if (r != curr) { atomicAdd(&dst[(size_t)curr * LVN + lvl], s); s = 0.f; curr = r; }
                    s += vv;
                }
                atomicAdd(&dst[(size_t)curr * LVN + lvl], s);
            }
        }
        __syncthreads();   // B5: Twd/rows_s/rad safe to overwrite next iteration

        // ---- rotate pipeline registers ----
        rowm = rowmn;
        row2 = row2n; col2 = col2n; ean = eann;
#pragma unroll
        for (int kf = 0; kf < 4; ++kf) acp[kf] = acn[kf];
    }
}

// ================= post: lat-band mean | wind finalize =================
__global__ __launch_bounds__(256)
void post_kernel(const float* __restrict__ agg, short* __restrict__ latb,
                 float* __restrict__ aggu, float* __restrict__ aggv,
                 const int* __restrict__ off)
{
    const int b = blockIdx.x, tid = threadIdx.x;
    if (b < NLAT) {
        __shared__ float part[256];
        const int j = tid & 127, half = tid >> 7;
        float s = 0.f;
        for (int lon = half * 120; lon < (half + 1) * 120; ++lon)
            s += agg[((size_t)b * NLON + lon) * HD + j];
        part[tid] = s;
        __syncthreads();
        if (tid < 128)
            latb[(size_t)b * HD + tid] = f2b((part[tid] + part[128 + tid]) * (1.0f / NLON));
        return;
    }
    int tt = (b - NLAT) * 256 + tid;
    if (tt >= NN * LVN) return;
    int n = tt / LVN;
    float c = fmaxf((float)(off[n + 1] - off[n]), 1.f);
    float xu = aggu[tt] / c, xv = aggv[tt] / c;
    aggu[tt] = fminf(fmaxf(xu, -100.f), 100.f);
    aggv[tt] = fminf(fmaxf(xv, -100.f), 100.f);
}

// ================= node kernel (direct-reg A) =================
__global__ __launch_bounds__(512, 4)
void node_mfma(const short* __restrict__ hb, const float* __restrict__ h,
               const short* __restrict__ latb,
               const float* __restrict__ bn1, const float* __restrict__ bn2,
               const short* __restrict__ wp, float* __restrict__ out)
{
    __shared__ short T1[128 * 128];
    const int tid = threadIdx.x, lane = tid & 63, w = tid >> 6;
    const int n0 = blockIdx.x * 128;
    const int mrow = 16 * w + (lane & 15);
    const int koff = 8 * (lane >> 4);
    const int n = n0 + mrow;
    const int nc = (n < NN) ? n : (NN - 1);
    const short* hp = hb + (size_t)nc * HD + koff;
    const float* ap = out + (size_t)nc * HD + koff;
    const short* lp = latb + (size_t)(nc / NLON) * HD + koff;

    f4 acc[8];
#pragma unroll
    for (int nf = 0; nf < 8; ++nf) {
        float bv = bn1[nf * 16 + (lane & 15)];
        acc[nf] = (f4){bv, bv, bv, bv};
    }
#pragma unroll
    for (int kf = 0; kf < 4; ++kf) {
        short8 a = *(const short8*)(hp + kf * 32);
        const short8* wr = (const short8*)(wp + OFF_WN1 + (size_t)kf * 8 * 512) + lane;
#pragma unroll
        for (int nf = 0; nf < 8; ++nf)
            acc[nf] = __builtin_amdgcn_mfma_f32_16x16x32_bf16(a, wr[nf * 64], acc[nf], 0, 0, 0);
    }
#pragma unroll
    for (int kf = 0; kf < 4; ++kf) {
        short8 a;
#pragma unroll
        for (int j = 0; j < 8; ++j) a[j] = f2b(ap[kf * 32 + j]);
        const short8* wr = (const short8*)(wp + OFF_WN1 + (size_t)(kf + 4) * 8 * 512) + lane;
#pragma unroll
        for (int nf = 0; nf < 8; ++nf)
            acc[nf] = __builtin_amdgcn_mfma_f32_16x16x32_bf16(a, wr[nf * 64], acc[nf], 0, 0, 0);
    }
#pragma unroll
    for (int kf = 0; kf < 4; ++kf) {
        short8 a = *(const short8*)(lp + kf * 32);
        const short8* wr = (const short8*)(wp + OFF_WN1 + (size_t)(kf + 8) * 8 * 512) + lane;
#pragma unroll
        for (int nf = 0; nf < 8; ++nf)
            acc[nf] = __builtin_amdgcn_mfma_f32_16x16x32_bf16(a, wr[nf * 64], acc[nf], 0, 0, 0);
    }
    store_tile<8>(T1, 256, acc, w, lane);
    layer_gemm<4, 8>(T1, 256, wp + OFF_WN2, bn2, acc, w, lane);

    const int rb = 16 * w + ((lane >> 4) << 2), cb = lane & 15;
#pragma unroll
    for (int nf = 0; nf < 8; ++nf)
#pragma unroll
        for (int r = 0; r < 4; ++r) {
            int gn = n0 + rb + r;
            if (gn < NN) {
                int colj = nf * 16 + cb;
                out[(size_t)gn * HD + colj] = acc[nf][r] + h[(size_t)gn * HD + colj];
            }
        }
}

extern "C" void kernel_launch(void* const* d_in, const int* in_sizes, int n_in,
                              void* d_out, int out_size, void* d_ws, size_t ws_size,
                              hipStream_t stream)
{
    const float* h   = (const float*)d_in[0];
    const float* u   = (const float*)d_in[1];
    const float* v   = (const float*)d_in[2];
    const float* ea  = (const float*)d_in[3];
    const float* We1 = (const float*)d_in[4];
    const float* be1 = (const float*)d_in[5];
    const float* We2 = (const float*)d_in[6];
    const float* be2 = (const float*)d_in[7];
    const float* Wn1 = (const float*)d_in[8];
    const float* bn1 = (const float*)d_in[9];
    const float* Wn2 = (const float*)d_in[10];
    const float* bn2 = (const float*)d_in[11];
    const float* Wc1 = (const float*)d_in[12];
    const float* bc1 = (const float*)d_in[13];
    const float* Wcl = (const float*)d_in[14];
    const int*   eidx = (const int*)d_in[15];

    float* out  = (float*)d_out;
    float* agg  = out;                       // [NN,HD]: agg accum, then h_out
    float* aggu = out + (size_t)NN * HD;
    float* aggv = aggu + (size_t)NN * LVN;

    // ---- workspace layout (no overlaps) ----
    char* p = (char*)d_ws;
    short* wp  = (short*)p;                  p += (size_t)WP_SHORTS * 2;
    int*   off = (int*)p;                    p += (size_t)(NN + 1) * 4;
    int*   csr = (int*)p;                    p += (size_t)EE * 4;
    p = (char*)(((size_t)p + 15) & ~(size_t)15);
    short* hb  = (short*)p;                  p += (size_t)NN * HD * 2;
    float* uvr = (float*)p;                  p += (size_t)NN * 36 * 4;
    short* latb = (short*)p;                 p += (size_t)NLAT * HD * 2;
    p = (char*)(((size_t)p + 15) & ~(size_t)15);
    int*   cnt = (int*)p;                    p += (size_t)NN * 4;
    int*   cur = (int*)p;

    hipMemsetAsync(d_out, 0, (size_t)out_size * sizeof(float), stream);
    hipMemsetAsync(cnt, 0, (size_t)2 * NN * sizeof(int), stream);

    setup_kernel<<<SB_HIST + SB_HCAST + SB_UV + SB_WP, 256, 0, stream>>>(
        eidx, cnt, h, hb, u, v, uvr, We1, We2, Wc1, Wcl, Wn1, Wn2, wp);
    scan_kernel<<<1, 1024, 0, stream>>>(cnt, off);
    scatter_kernel<<<EE / 256, 256, 0, stream>>>(eidx, off, cur, csr);

    edge_mfma<<<EGRID, 512, 0, stream>>>(hb, uvr, ea, be1, be2, bc1,
                                         wp, eidx, csr, agg, aggu, aggv);

    post_kernel<<<NLAT + (NN * LVN + 255) / 256, 256, 0, stream>>>(
        agg, latb, aggu, aggv, off);

    node_mfma<<<(NN + 127) / 128, 512, 0, stream>>>(hb, h, latb, bn1, bn2, wp, agg);
}

// Round 7
// 345.013 us; speedup vs baseline: 5.2776x; 5.2776x over previous
//
#include <hip/hip_runtime.h>
#include <hip/hip_bf16.h>
#include <math.h>

#define NN   29040
#define NLAT 121
#define NLON 240
#define HD   128
#define LVN  11
#define EE   464640

typedef __attribute__((ext_vector_type(8))) short short8;
typedef __attribute__((ext_vector_type(4))) float f4;

// packed-weight offsets (in shorts) inside wp buffer
#define OFF_WE1 0          // 10 kf x 8 nf  = 80 frags
#define OFF_WE2 40960      // 4 x 8 = 32
#define OFF_WC1 57344      // 4 x 8 = 32
#define OFF_WCL 73728      // 4 x 2 = 8
#define OFF_WN1 77824      // 12 x 8 = 96
#define OFF_WN2 126976     // 4 x 8 = 32
#define WP_SHORTS 143360

__device__ inline short f2b(float x) {
    union { __hip_bfloat16 b; short s; } v;
    v.b = __float2bfloat16(x);
    return v.s;
}
__device__ inline float b2f(unsigned short b) {
    union { unsigned u; float f; } v; v.u = ((unsigned)b) << 16;
    return v.f;
}

// ================= fused setup: hist | h-cast | uv-prep | weight-pack =================
#define SB_HIST  1815
#define SB_HCAST 1815
#define SB_UV    114
#define SB_WP    70

__global__ __launch_bounds__(256)
void setup_kernel(const int* __restrict__ eidx, int* __restrict__ cnt,
                  const float* __restrict__ h, short* __restrict__ hb,
                  const float* __restrict__ u, const float* __restrict__ v,
                  float* __restrict__ uvrec,
                  const float* __restrict__ We1, const float* __restrict__ We2,
                  const float* __restrict__ Wc1, const float* __restrict__ Wcl,
                  const float* __restrict__ Wn1, const float* __restrict__ Wn2,
                  short* __restrict__ wp)
{
    const int b = blockIdx.x, tid = threadIdx.x;
    if (b < SB_HIST) {
        int e = b * 256 + tid;
        atomicAdd(&cnt[eidx[e]], 1);
        return;
    }
    if (b < SB_HIST + SB_HCAST) {
        int idx = (b - SB_HIST) * 256 + tid;          // 8 elems each
        const float4* hf = (const float4*)h;
        float4 a = hf[idx * 2], c = hf[idx * 2 + 1];
        short8 o;
        o[0] = f2b(a.x); o[1] = f2b(a.y); o[2] = f2b(a.z); o[3] = f2b(a.w);
        o[4] = f2b(c.x); o[5] = f2b(c.y); o[6] = f2b(c.z); o[7] = f2b(c.w);
        ((short8*)hb)[idx] = o;
        return;
    }
    if (b < SB_HIST + SB_HCAST + SB_UV) {
        int n = (b - SB_HIST - SB_HCAST) * 256 + tid;
        if (n >= NN) return;
        float* r = uvrec + (size_t)n * 36;
        float un = 0.f, vn = 0.f;
#pragma unroll
        for (int l = 0; l < LVN; ++l) {
            float uu = u[n * LVN + l], vv = v[n * LVN + l];
            float s = sqrtf(uu * uu + vv * vv);
            r[l]      = uu / s;
            r[11 + l] = vv / s;
            r[22 + l] = s;
            un += uu * uu; vn += vv * vv;
        }
        r[33] = sqrtf(un);
        r[34] = sqrtf(vn);
        r[35] = 0.f;
        return;
    }
    // weight pack: 4 fragments per block
    {
        int fg = (b - SB_HIST - SB_HCAST - SB_UV) * 4 + (tid >> 6);   // 0..279
        const int l = tid & 63;
        int kind, f, base;
        if (fg < 80)       { kind = 0; f = fg;       base = OFF_WE1; }
        else if (fg < 112) { kind = 1; f = fg - 80;  base = OFF_WE2; }
        else if (fg < 144) { kind = 2; f = fg - 112; base = OFF_WC1; }
        else if (fg < 152) { kind = 3; f = fg - 144; base = OFF_WCL; }
        else if (fg < 248) { kind = 4; f = fg - 152; base = OFF_WN1; }
        else               { kind = 5; f = fg - 248; base = OFF_WN2; }
        const int nfw = (kind == 3) ? 2 : 8;
        const int kf = f / nfw, nf = f % nfw;
        short* dst = wp + base + (size_t)f * 512 + l * 8;
        for (int i = 0; i < 8; ++i) {
            int k = kf * 32 + ((l >> 4) << 3) + i;
            int n = nf * 16 + (l & 15);
            float val = 0.f;
            if (kind == 0) {
                int r = (k < 33) ? (256 + k) : (k == 33 ? 289 : (k < 64 ? -1 : k - 64));
                if (r >= 0) val = We1[r * HD + n];
            } else if (kind == 1) val = We2[k * HD + n];
            else if (kind == 2)  val = Wc1[k * HD + n];
            else if (kind == 3)  { if (n < 22) val = Wcl[k * 22 + n]; }
            else if (kind == 4)  val = Wn1[k * HD + n];
            else                 val = Wn2[k * HD + n];
            dst[i] = f2b(val);
        }
    }
}

// ================= CSR scan + scatter =================
__global__ __launch_bounds__(1024)
void scan_kernel(const int* __restrict__ cnt, int* __restrict__ off)
{
    __shared__ int part[1024];
    const int tid = threadIdx.x;
    const int CH = 29;
    int lo = tid * CH, hi = min(lo + CH, NN);
    int s = 0;
    for (int i = lo; i < hi; ++i) s += cnt[i];
    part[tid] = s;
    __syncthreads();
    for (int d = 1; d < 1024; d <<= 1) {
        int vv = (tid >= d) ? part[tid - d] : 0;
        __syncthreads();
        part[tid] += vv;
        __syncthreads();
    }
    int run = (tid == 0) ? 0 : part[tid - 1];
    for (int i = lo; i < hi; ++i) { off[i] = run; run += cnt[i]; }
    if (tid == 1023) off[NN] = run;
}

__global__ __launch_bounds__(256)
void scatter_kernel(const int* __restrict__ eidx, const int* __restrict__ off,
                    int* __restrict__ cur, int* __restrict__ csr)
{
    int e = blockIdx.x * 256 + threadIdx.x;
    if (e >= EE) return;
    int row = eidx[e];
    int p = atomicAdd(&cur[row], 1);
    csr[off[row] + p] = e;
}

// ================= GEMM helpers =================
template<int KF, int NF>
__device__ inline void layer_gemm(const short* At, int rs, const short* Wp,
                                  const float* bias, f4* acc, int w, int lane)
{
    const int m = 16 * w + (lane & 15);
    const char* arow = (const char*)At + m * rs;
    const int sw = (m & 7) << 4;
    const int kb = (lane >> 4) << 4;
#pragma unroll
    for (int nf = 0; nf < NF; ++nf) {
        float bv = bias ? bias[nf * 16 + (lane & 15)] : 0.f;
        acc[nf] = (f4){bv, bv, bv, bv};
    }
#pragma unroll
    for (int kf = 0; kf < KF; ++kf) {
        short8 a = *(const short8*)(arow + ((kf * 64 + kb) ^ sw));
        const short8* wr = (const short8*)(Wp + (size_t)kf * NF * 512) + lane;
#pragma unroll
        for (int nf = 0; nf < NF; ++nf) {
            short8 bfr = wr[nf * 64];
            acc[nf] = __builtin_amdgcn_mfma_f32_16x16x32_bf16(a, bfr, acc[nf], 0, 0, 0);
        }
    }
}

template<int NF>
__device__ inline void store_tile(short* tile, int rs, const f4* acc, int w, int lane)
{
    const int rb = 16 * w + ((lane >> 4) << 2);
    const int cb = (lane & 15) * 2;
#pragma unroll
    for (int nf = 0; nf < NF; ++nf)
#pragma unroll
        for (int r = 0; r < 4; ++r) {
            int row = rb + r;
            float vv = fmaxf(acc[nf][r], 0.f);
            *(short*)((char*)tile + row * rs + ((cb + nf * 32) ^ ((row & 7) << 4))) = f2b(vv);
        }
}

// ================= edge kernel: 64-edge tiles, 4 waves, hoisted h-gather =================
// (256,4): 4 waves/EU floor -> 128-VGPR budget with 4 blocks/CU. The round-5/6
// cross-tile pipeline spilled at any budget the allocator would honor; this is
// the round-4 structure with the random h[row/col] gather issued at kernel
// start so its latency hides under the wd build + barrier.
__global__ __launch_bounds__(256, 4)
void edge_mfma(const short* __restrict__ hb, const float* __restrict__ uvrec,
               const float* __restrict__ ea,
               const float* __restrict__ be1, const float* __restrict__ be2,
               const float* __restrict__ bc1,
               const short* __restrict__ wp,
               const int* __restrict__ eidx, const int* __restrict__ csr,
               float* __restrict__ agg, float* __restrict__ aggu,
               float* __restrict__ aggv)
{
    __shared__ short Twd[64 * 64];     // 8 KB wd tile (128B rows); later O22 f32
    __shared__ short T1[64 * 128];     // 16 KB (256B rows)
    __shared__ int   rows_s[64];
    __shared__ float radu_s[64], radv_s[64];

    const int tid = threadIdx.x, lane = tid & 63, w = tid >> 6;   // w in 0..3
    const int e0 = blockIdx.x * 64;
    const int mrow = 16 * w + (lane & 15);       // 0..63
    const int koff = 8 * (lane >> 4);
    const int sw   = (mrow & 7) << 4;

    // ---- own-row index chain + EARLY h fragment gather (issue-early/use-late) ----
    int e1 = csr[e0 + mrow];
    int rowm = eidx[e1], colm = eidx[EE + e1];
    short8 ar[4], ac[4];
    {
        const short* hr = hb + (size_t)rowm * HD + koff;
        const short* hc = hb + (size_t)colm * HD + koff;
#pragma unroll
        for (int kf = 0; kf < 4; ++kf) {
            ar[kf] = *(const short8*)(hr + kf * 32);
            ac[kf] = *(const short8*)(hc + kf * 32);
        }
    }

    // ---- wd tile build (4 threads per row), overlaps the h-gather latency ----
    {
        const int m2 = tid >> 2, q = tid & 3;    // m2 0..63
        const int sw2 = (m2 & 7) << 4;
        int e2 = csr[e0 + m2];
        int row2 = eidx[e2], col2 = eidx[EE + e2];
        const float* rc = uvrec + (size_t)col2 * 36;
        const float* rr = uvrec + (size_t)row2 * 36;
        char* arow = (char*)(Twd + m2 * 64);
        short8 z = {0, 0, 0, 0, 0, 0, 0, 0};
        *(short8*)(arow + q * 32) = z;
        *(short8*)(arow + q * 32 + 16) = z;
        for (int l = q; l < LVN; l += 4) {
            float rel = rc[l] * rr[l] + rc[11 + l] * rr[11 + l];
            *(short*)(arow + ((2 * l) ^ sw2))        = f2b(rel);
            *(short*)(arow + ((2 * (11 + l)) ^ sw2)) = f2b(rc[22 + l]);
            *(short*)(arow + ((2 * (22 + l)) ^ sw2)) = f2b(rr[22 + l]);
        }
        if (q == 0) { rows_s[m2] = row2; radu_s[m2] = rc[33]; radv_s[m2] = rc[34]; }
        if (q == 3) *(short*)(arow + ((2 * 33) ^ sw2)) = f2b(ea[e2]);
    }
    __syncthreads();   // B1: Twd/rows_s/rad visible

    // ==== edge MLP layer 1 ====
    f4 acc[8];
#pragma unroll
    for (int nf = 0; nf < 8; ++nf) {
        float bv = be1[nf * 16 + (lane & 15)];
        acc[nf] = (f4){bv, bv, bv, bv};
    }
    {
        const char* awd = (const char*)(Twd + mrow * 64);
#pragma unroll
        for (int kf = 0; kf < 2; ++kf) {
            short8 a = *(const short8*)(awd + ((kf * 64 + 2 * koff) ^ sw));
            const short8* wr = (const short8*)(wp + OFF_WE1 + (size_t)kf * 8 * 512) + lane;
#pragma unroll
            for (int nf = 0; nf < 8; ++nf)
                acc[nf] = __builtin_amdgcn_mfma_f32_16x16x32_bf16(a, wr[nf * 64], acc[nf], 0, 0, 0);
        }
#pragma unroll
        for (int kf = 0; kf < 4; ++kf) {
            const short8* wr = (const short8*)(wp + OFF_WE1 + (size_t)(kf + 2) * 8 * 512) + lane;
#pragma unroll
            for (int nf = 0; nf < 8; ++nf)
                acc[nf] = __builtin_amdgcn_mfma_f32_16x16x32_bf16(ar[kf], wr[nf * 64], acc[nf], 0, 0, 0);
        }
#pragma unroll
        for (int kf = 0; kf < 4; ++kf) {
            const short8* wr = (const short8*)(wp + OFF_WE1 + (size_t)(kf + 6) * 8 * 512) + lane;
#pragma unroll
            for (int nf = 0; nf < 8; ++nf)
                acc[nf] = __builtin_amdgcn_mfma_f32_16x16x32_bf16(ac[kf], wr[nf * 64], acc[nf], 0, 0, 0);
        }
    }
    store_tile<8>(T1, 256, acc, w, lane);     // Y1 (wave-private rows)

    // ==== edge MLP layer 2 -> EF (wave-private, no barrier) ====
    layer_gemm<4, 8>(T1, 256, wp + OFF_WE2, be2, acc, w, lane);
    store_tile<8>(T1, 256, acc, w, lane);

    // ==== coord MLP layer 1 (wave-private EF rows) ====
    f4 accC[8];
    layer_gemm<4, 8>(T1, 256, wp + OFF_WC1, bc1, accC, w, lane);

    __syncthreads();   // B2: EF tile complete
    // ==== agg: segmented reduce over sorted rows ====
    {
        const int n = tid & 127, qq = tid >> 7;
        const int m0 = qq * 32;
        int curr = rows_s[m0]; float s = 0.f;
        for (int m = m0; m < m0 + 32; ++m) {
            int r = rows_s[m];
            float vv = b2f(*(const unsigned short*)((const char*)(T1 + m * 128) + ((2 * n) ^ ((m & 7) << 4))));
            if (r != curr) { atomicAdd(&agg[(size_t)curr * HD + n], s); s = 0.f; curr = r; }
            s += vv;
        }
        atomicAdd(&agg[(size_t)curr * HD + n], s);
    }
    __syncthreads();   // B3: EF reads done, T1 reusable

    // ==== coord C1 -> T1, final CL layer, O22 ====
    store_tile<8>(T1, 256, accC, w, lane);
    layer_gemm<4, 2>(T1, 256, wp + OFF_WCL, (const float*)nullptr, accC, w, lane);
    float* O22 = (float*)Twd;                  // 64x32 f32 = 8 KB (wd tile dead)
    {
        const int rb = 16 * w + ((lane >> 4) << 2), cb = lane & 15;
#pragma unroll
        for (int nf = 0; nf < 2; ++nf)
#pragma unroll
            for (int r = 0; r < 4; ++r)
                O22[(rb + r) * 32 + nf * 16 + cb] = accC[nf][r];
    }
    __syncthreads();   // B4: O22 visible

    // ==== wind: segmented reduce (8 groups x 8 rows) ====
    {
        const int c = tid & 31, qq = tid >> 5;
        if (c < 22) {
            const bool isU = c < LVN;
            const int lvl = isU ? c : c - LVN;
            float* dst = isU ? aggu : aggv;
            const float* radp = isU ? radu_s : radv_s;
            const int m0 = qq * 8;
            int curr = rows_s[m0]; float s = 0.f;
            for (int m = m0; m < m0 + 8; ++m) {
                int r = rows_s[m];
                float vv = O22[m * 32 + c] * radp[m];
                if (r != curr) { atomicAdd(&dst[(size_t)curr * LVN + lvl], s); s = 0.f; curr = r; }
                s += vv;
            }
            atomicAdd(&dst[(size_t)curr * LVN + lvl], s);
        }
    }
}

// ================= post: lat-band mean | wind finalize =================
__global__ __launch_bounds__(256)
void post_kernel(const float* __restrict__ agg, short* __restrict__ latb,
                 float* __restrict__ aggu, float* __restrict__ aggv,
                 const int* __restrict__ off)
{
    const int b = blockIdx.x, tid = threadIdx.x;
    if (b < NLAT) {
        __shared__ float part[256];
        const int j = tid & 127, half = tid >> 7;
        float s = 0.f;
        for (int lon = half * 120; lon < (half + 1) * 120; ++lon)
            s += agg[((size_t)b * NLON + lon) * HD + j];
        part[tid] = s;
        __syncthreads();
        if (tid < 128)
            latb[(size_t)b * HD + tid] = f2b((part[tid] + part[128 + tid]) * (1.0f / NLON));
        return;
    }
    int tt = (b - NLAT) * 256 + tid;
    if (tt >= NN * LVN) return;
    int n = tt / LVN;
    float c = fmaxf((float)(off[n + 1] - off[n]), 1.f);
    float xu = aggu[tt] / c, xv = aggv[tt] / c;
    aggu[tt] = fminf(fmaxf(xu, -100.f), 100.f);
    aggv[tt] = fminf(fmaxf(xv, -100.f), 100.f);
}

// ================= node kernel (direct-reg A) =================
__global__ __launch_bounds__(512, 4)
void node_mfma(const short* __restrict__ hb, const float* __restrict__ h,
               const short* __restrict__ latb,
               const float* __restrict__ bn1, const float* __restrict__ bn2,
               const short* __restrict__ wp, float* __restrict__ out)
{
    __shared__ short T1[128 * 128];
    const int tid = threadIdx.x, lane = tid & 63, w = tid >> 6;
    const int n0 = blockIdx.x * 128;
    const int mrow = 16 * w + (lane & 15);
    const int koff = 8 * (lane >> 4);
    const int n = n0 + mrow;
    const int nc = (n < NN) ? n : (NN - 1);
    const short* hp = hb + (size_t)nc * HD + koff;
    const float* ap = out + (size_t)nc * HD + koff;
    const short* lp = latb + (size_t)(nc / NLON) * HD + koff;

    f4 acc[8];
#pragma unroll
    for (int nf = 0; nf < 8; ++nf) {
        float bv = bn1[nf * 16 + (lane & 15)];
        acc[nf] = (f4){bv, bv, bv, bv};
    }
#pragma unroll
    for (int kf = 0; kf < 4; ++kf) {
        short8 a = *(const short8*)(hp + kf * 32);
        const short8* wr = (const short8*)(wp + OFF_WN1 + (size_t)kf * 8 * 512) + lane;
#pragma unroll
        for (int nf = 0; nf < 8; ++nf)
            acc[nf] = __builtin_amdgcn_mfma_f32_16x16x32_bf16(a, wr[nf * 64], acc[nf], 0, 0, 0);
    }
#pragma unroll
    for (int kf = 0; kf < 4; ++kf) {
        short8 a;
#pragma unroll
        for (int j = 0; j < 8; ++j) a[j] = f2b(ap[kf * 32 + j]);
        const short8* wr = (const short8*)(wp + OFF_WN1 + (size_t)(kf + 4) * 8 * 512) + lane;
#pragma unroll
        for (int nf = 0; nf < 8; ++nf)
            acc[nf] = __builtin_amdgcn_mfma_f32_16x16x32_bf16(a, wr[nf * 64], acc[nf], 0, 0, 0);
    }
#pragma unroll
    for (int kf = 0; kf < 4; ++kf) {
        short8 a = *(const short8*)(lp + kf * 32);
        const short8* wr = (const short8*)(wp + OFF_WN1 + (size_t)(kf + 8) * 8 * 512) + lane;
#pragma unroll
        for (int nf = 0; nf < 8; ++nf)
            acc[nf] = __builtin_amdgcn_mfma_f32_16x16x32_bf16(a, wr[nf * 64], acc[nf], 0, 0, 0);
    }
    store_tile<8>(T1, 256, acc, w, lane);
    layer_gemm<4, 8>(T1, 256, wp + OFF_WN2, bn2, acc, w, lane);

    const int rb = 16 * w + ((lane >> 4) << 2), cb = lane & 15;
#pragma unroll
    for (int nf = 0; nf < 8; ++nf)
#pragma unroll
        for (int r = 0; r < 4; ++r) {
            int gn = n0 + rb + r;
            if (gn < NN) {
                int colj = nf * 16 + cb;
                out[(size_t)gn * HD + colj] = acc[nf][r] + h[(size_t)gn * HD + colj];
            }
        }
}

extern "C" void kernel_launch(void* const* d_in, const int* in_sizes, int n_in,
                              void* d_out, int out_size, void* d_ws, size_t ws_size,
                              hipStream_t stream)
{
    const float* h   = (const float*)d_in[0];
    const float* u   = (const float*)d_in[1];
    const float* v   = (const float*)d_in[2];
    const float* ea  = (const float*)d_in[3];
    const float* We1 = (const float*)d_in[4];
    const float* be1 = (const float*)d_in[5];
    const float* We2 = (const float*)d_in[6];
    const float* be2 = (const float*)d_in[7];
    const float* Wn1 = (const float*)d_in[8];
    const float* bn1 = (const float*)d_in[9];
    const float* Wn2 = (const float*)d_in[10];
    const float* bn2 = (const float*)d_in[11];
    const float* Wc1 = (const float*)d_in[12];
    const float* bc1 = (const float*)d_in[13];
    const float* Wcl = (const float*)d_in[14];
    const int*   eidx = (const int*)d_in[15];

    float* out  = (float*)d_out;
    float* agg  = out;                       // [NN,HD]: agg accum, then h_out
    float* aggu = out + (size_t)NN * HD;
    float* aggv = aggu + (size_t)NN * LVN;

    // ---- workspace layout (no overlaps) ----
    char* p = (char*)d_ws;
    short* wp  = (short*)p;                  p += (size_t)WP_SHORTS * 2;
    int*   off = (int*)p;                    p += (size_t)(NN + 1) * 4;
    int*   csr = (int*)p;                    p += (size_t)EE * 4;
    p = (char*)(((size_t)p + 15) & ~(size_t)15);
    short* hb  = (short*)p;                  p += (size_t)NN * HD * 2;
    float* uvr = (float*)p;                  p += (size_t)NN * 36 * 4;
    short* latb = (short*)p;                 p += (size_t)NLAT * HD * 2;
    p = (char*)(((size_t)p + 15) & ~(size_t)15);
    int*   cnt = (int*)p;                    p += (size_t)NN * 4;
    int*   cur = (int*)p;

    hipMemsetAsync(d_out, 0, (size_t)out_size * sizeof(float), stream);
    hipMemsetAsync(cnt, 0, (size_t)2 * NN * sizeof(int), stream);

    setup_kernel<<<SB_HIST + SB_HCAST + SB_UV + SB_WP, 256, 0, stream>>>(
        eidx, cnt, h, hb, u, v, uvr, We1, We2, Wc1, Wcl, Wn1, Wn2, wp);
    scan_kernel<<<1, 1024, 0, stream>>>(cnt, off);
    scatter_kernel<<<EE / 256, 256, 0, stream>>>(eidx, off, cur, csr);

    edge_mfma<<<EE / 64, 256, 0, stream>>>(hb, uvr, ea, be1, be2, bc1,
                                           wp, eidx, csr, agg, aggu, aggv);

    post_kernel<<<NLAT + (NN * LVN + 255) / 256, 256, 0, stream>>>(
        agg, latb, aggu, aggv, off);

    node_mfma<<<(NN + 127) / 128, 512, 0, stream>>>(hb, h, latb, bn1, bn2, wp, agg);
}

// Round 8
// 340.450 us; speedup vs baseline: 5.3484x; 1.0134x over previous
//
#include <hip/hip_runtime.h>
#include <hip/hip_bf16.h>
#include <math.h>

#define NN   29040
#define NLAT 121
#define NLON 240
#define HD   128
#define LVN  11
#define EE   464640

typedef __attribute__((ext_vector_type(8))) short short8;
typedef __attribute__((ext_vector_type(4))) float f4;

// packed-weight offsets (in shorts) inside wp buffer
#define OFF_WE1 0          // 10 kf x 8 nf  = 80 frags
#define OFF_WE2 40960      // 4 x 8 = 32
#define OFF_WC1 57344      // 4 x 8 = 32
#define OFF_WCL 73728      // 4 x 2 = 8
#define OFF_WN1 77824      // 12 x 8 = 96
#define OFF_WN2 126976     // 4 x 8 = 32
#define WP_SHORTS 143360

__device__ inline short f2b(float x) {
    union { __hip_bfloat16 b; short s; } v;
    v.b = __float2bfloat16(x);
    return v.s;
}
__device__ inline float b2f(unsigned short b) {
    union { unsigned u; float f; } v; v.u = ((unsigned)b) << 16;
    return v.f;
}
__device__ inline unsigned pk2(float lo, float hi) {
    return ((unsigned)(unsigned short)f2b(hi) << 16) | (unsigned short)f2b(lo);
}
__device__ inline float asf(unsigned u) {
    union { unsigned u; float f; } v; v.u = u;
    return v.f;
}

// ================= fused setup: hist | h-cast | uv-prep | weight-pack =================
#define SB_HIST  1815
#define SB_HCAST 1815
#define SB_UV    114
#define SB_WP    70

__global__ __launch_bounds__(256)
void setup_kernel(const int* __restrict__ eidx, int* __restrict__ cnt,
                  const float* __restrict__ h, short* __restrict__ hb,
                  const float* __restrict__ u, const float* __restrict__ v,
                  float* __restrict__ uvrec,
                  const float* __restrict__ We1, const float* __restrict__ We2,
                  const float* __restrict__ Wc1, const float* __restrict__ Wcl,
                  const float* __restrict__ Wn1, const float* __restrict__ Wn2,
                  short* __restrict__ wp)
{
    const int b = blockIdx.x, tid = threadIdx.x;
    if (b < SB_HIST) {
        int e = b * 256 + tid;
        atomicAdd(&cnt[eidx[e]], 1);
        return;
    }
    if (b < SB_HIST + SB_HCAST) {
        int idx = (b - SB_HIST) * 256 + tid;          // 8 elems each
        const float4* hf = (const float4*)h;
        float4 a = hf[idx * 2], c = hf[idx * 2 + 1];
        short8 o;
        o[0] = f2b(a.x); o[1] = f2b(a.y); o[2] = f2b(a.z); o[3] = f2b(a.w);
        o[4] = f2b(c.x); o[5] = f2b(c.y); o[6] = f2b(c.z); o[7] = f2b(c.w);
        ((short8*)hb)[idx] = o;
        return;
    }
    if (b < SB_HIST + SB_HCAST + SB_UV) {
        int n = (b - SB_HIST - SB_HCAST) * 256 + tid;
        if (n >= NN) return;
        float* r = uvrec + (size_t)n * 36;
        float un = 0.f, vn = 0.f;
#pragma unroll
        for (int l = 0; l < LVN; ++l) {
            float uu = u[n * LVN + l], vv = v[n * LVN + l];
            float s = sqrtf(uu * uu + vv * vv);
            r[l]      = uu / s;
            r[11 + l] = vv / s;
            r[22 + l] = s;
            un += uu * uu; vn += vv * vv;
        }
        r[33] = sqrtf(un);
        r[34] = sqrtf(vn);
        r[35] = 0.f;
        return;
    }
    // weight pack: 4 fragments per block.
    // kinds {1,2,3,5} consume PACKED tiles -> k-permuted fragment order:
    //   k = kf*32 + (i&1)*16 + 4*(l>>4) + (i>>1)
    // kinds {0,4} consume unpacked data -> k = kf*32 + 8*(l>>4) + i
    {
        int fg = (b - SB_HIST - SB_HCAST - SB_UV) * 4 + (tid >> 6);   // 0..279
        const int l = tid & 63;
        int kind, f, base;
        if (fg < 80)       { kind = 0; f = fg;       base = OFF_WE1; }
        else if (fg < 112) { kind = 1; f = fg - 80;  base = OFF_WE2; }
        else if (fg < 144) { kind = 2; f = fg - 112; base = OFF_WC1; }
        else if (fg < 152) { kind = 3; f = fg - 144; base = OFF_WCL; }
        else if (fg < 248) { kind = 4; f = fg - 152; base = OFF_WN1; }
        else               { kind = 5; f = fg - 248; base = OFF_WN2; }
        const int nfw = (kind == 3) ? 2 : 8;
        const int kf = f / nfw, nf = f % nfw;
        const bool perm = (kind == 1) || (kind == 2) || (kind == 3) || (kind == 5);
        short* dst = wp + base + (size_t)f * 512 + l * 8;
        const int hgrp = l >> 4;
        for (int i = 0; i < 8; ++i) {
            int k = perm ? (kf * 32 + ((i & 1) << 4) + (hgrp << 2) + (i >> 1))
                         : (kf * 32 + (hgrp << 3) + i);
            int n = nf * 16 + (l & 15);
            float val = 0.f;
            if (kind == 0) {
                int r = (k < 33) ? (256 + k) : (k == 33 ? 289 : (k < 64 ? -1 : k - 64));
                if (r >= 0) val = We1[r * HD + n];
            } else if (kind == 1) val = We2[k * HD + n];
            else if (kind == 2)  val = Wc1[k * HD + n];
            else if (kind == 3)  { if (n < 22) val = Wcl[k * 22 + n]; }
            else if (kind == 4)  val = Wn1[k * HD + n];
            else                 val = Wn2[k * HD + n];
            dst[i] = f2b(val);
        }
    }
}

// ================= CSR scan + scatter =================
__global__ __launch_bounds__(1024)
void scan_kernel(const int* __restrict__ cnt, int* __restrict__ off)
{
    __shared__ int part[1024];
    const int tid = threadIdx.x;
    const int CH = 29;
    int lo = tid * CH, hi = min(lo + CH, NN);
    int s = 0;
    for (int i = lo; i < hi; ++i) s += cnt[i];
    part[tid] = s;
    __syncthreads();
    for (int d = 1; d < 1024; d <<= 1) {
        int vv = (tid >= d) ? part[tid - d] : 0;
        __syncthreads();
        part[tid] += vv;
        __syncthreads();
    }
    int run = (tid == 0) ? 0 : part[tid - 1];
    for (int i = lo; i < hi; ++i) { off[i] = run; run += cnt[i]; }
    if (tid == 1023) off[NN] = run;
}

__global__ __launch_bounds__(256)
void scatter_kernel(const int* __restrict__ eidx, const int* __restrict__ off,
                    int* __restrict__ cur, int* __restrict__ csr)
{
    int e = blockIdx.x * 256 + threadIdx.x;
    if (e >= EE) return;
    int row = eidx[e];
    int p = atomicAdd(&cur[row], 1);
    csr[off[row] + p] = e;
}

// ================= GEMM helpers =================
template<int KF, int NF>
__device__ inline void layer_gemm(const short* At, int rs, const short* Wp,
                                  const float* bias, f4* acc, int w, int lane)
{
    const int m = 16 * w + (lane & 15);
    const char* arow = (const char*)At + m * rs;
    const int sw = (m & 7) << 4;
    const int kb = (lane >> 4) << 4;
#pragma unroll
    for (int nf = 0; nf < NF; ++nf) {
        float bv = bias ? bias[nf * 16 + (lane & 15)] : 0.f;
        acc[nf] = (f4){bv, bv, bv, bv};
    }
#pragma unroll
    for (int kf = 0; kf < KF; ++kf) {
        short8 a = *(const short8*)(arow + ((kf * 64 + kb) ^ sw));
        const short8* wr = (const short8*)(Wp + (size_t)kf * NF * 512) + lane;
#pragma unroll
        for (int nf = 0; nf < NF; ++nf) {
            short8 bfr = wr[nf * 64];
            acc[nf] = __builtin_amdgcn_mfma_f32_16x16x32_bf16(a, bfr, acc[nf], 0, 0, 0);
        }
    }
}

// packed store: column pairs (2j,2j+1) -> one u32 (lo=2j, hi=2j+1), relu applied.
// physical short p = 32j + 2c + b  <->  logical col 32j + 16b + c
template<int NF>
__device__ inline void store_pk(short* tile, int rs, const f4* acc, int w, int lane)
{
    const int rb = 16 * w + ((lane >> 4) << 2);
    const int cb = (lane & 15) * 4;
#pragma unroll
    for (int j = 0; j < NF / 2; ++j)
#pragma unroll
        for (int r = 0; r < 4; ++r) {
            int row = rb + r;
            float lo = fmaxf(acc[2 * j][r], 0.f);
            float hi = fmaxf(acc[2 * j + 1][r], 0.f);
            *(unsigned*)((char*)tile + row * rs + ((j * 64 + cb) ^ ((row & 7) << 4))) = pk2(lo, hi);
        }
}

// ================= edge kernel: 64-edge tiles, 4 waves, hoisted h-gather =================
__global__ __launch_bounds__(256, 4)
void edge_mfma(const short* __restrict__ hb, const float* __restrict__ uvrec,
               const float* __restrict__ ea,
               const float* __restrict__ be1, const float* __restrict__ be2,
               const float* __restrict__ bc1,
               const short* __restrict__ wp,
               const int* __restrict__ eidx, const int* __restrict__ csr,
               float* __restrict__ agg, float* __restrict__ aggu,
               float* __restrict__ aggv)
{
    __shared__ short Twd[64 * 64];     // 8 KB wd tile (128B rows); later O22 f32
    __shared__ short T1[64 * 128];     // 16 KB (256B rows), packed layout
    __shared__ int   rows_s[64];
    __shared__ float radu_s[64], radv_s[64];

    const int tid = threadIdx.x, lane = tid & 63, w = tid >> 6;   // w in 0..3
    const int e0 = blockIdx.x * 64;
    const int mrow = 16 * w + (lane & 15);       // 0..63
    const int koff = 8 * (lane >> 4);
    const int sw   = (mrow & 7) << 4;

    // ---- own-row index chain + EARLY h fragment gather ----
    int e1 = csr[e0 + mrow];
    int rowm = eidx[e1], colm = eidx[EE + e1];
    short8 ar[4], ac[4];
    {
        const short* hr = hb + (size_t)rowm * HD + koff;
        const short* hc = hb + (size_t)colm * HD + koff;
#pragma unroll
        for (int kf = 0; kf < 4; ++kf) {
            ar[kf] = *(const short8*)(hr + kf * 32);
            ac[kf] = *(const short8*)(hc + kf * 32);
        }
    }

    // ---- wd tile build (4 threads per row) ----
    {
        const int m2 = tid >> 2, q = tid & 3;    // m2 0..63
        const int sw2 = (m2 & 7) << 4;
        int e2 = csr[e0 + m2];
        int row2 = eidx[e2], col2 = eidx[EE + e2];
        const float* rc = uvrec + (size_t)col2 * 36;
        const float* rr = uvrec + (size_t)row2 * 36;
        char* arow = (char*)(Twd + m2 * 64);
        short8 z = {0, 0, 0, 0, 0, 0, 0, 0};
        *(short8*)(arow + q * 32) = z;
        *(short8*)(arow + q * 32 + 16) = z;
        for (int l = q; l < LVN; l += 4) {
            float rel = rc[l] * rr[l] + rc[11 + l] * rr[11 + l];
            *(short*)(arow + ((2 * l) ^ sw2))        = f2b(rel);
            *(short*)(arow + ((2 * (11 + l)) ^ sw2)) = f2b(rc[22 + l]);
            *(short*)(arow + ((2 * (22 + l)) ^ sw2)) = f2b(rr[22 + l]);
        }
        if (q == 0) { rows_s[m2] = row2; radu_s[m2] = rc[33]; radv_s[m2] = rc[34]; }
        if (q == 3) *(short*)(arow + ((2 * 33) ^ sw2)) = f2b(ea[e2]);
    }
    __syncthreads();   // B1: Twd/rows_s/rad visible

    // ==== edge MLP layer 1 ====
    f4 acc[8];
#pragma unroll
    for (int nf = 0; nf < 8; ++nf) {
        float bv = be1[nf * 16 + (lane & 15)];
        acc[nf] = (f4){bv, bv, bv, bv};
    }
    {
        const char* awd = (const char*)(Twd + mrow * 64);
#pragma unroll
        for (int kf = 0; kf < 2; ++kf) {
            short8 a = *(const short8*)(awd + ((kf * 64 + 2 * koff) ^ sw));
            const short8* wr = (const short8*)(wp + OFF_WE1 + (size_t)kf * 8 * 512) + lane;
#pragma unroll
            for (int nf = 0; nf < 8; ++nf)
                acc[nf] = __builtin_amdgcn_mfma_f32_16x16x32_bf16(a, wr[nf * 64], acc[nf], 0, 0, 0);
        }
#pragma unroll
        for (int kf = 0; kf < 4; ++kf) {
            const short8* wr = (const short8*)(wp + OFF_WE1 + (size_t)(kf + 2) * 8 * 512) + lane;
#pragma unroll
            for (int nf = 0; nf < 8; ++nf)
                acc[nf] = __builtin_amdgcn_mfma_f32_16x16x32_bf16(ar[kf], wr[nf * 64], acc[nf], 0, 0, 0);
        }
#pragma unroll
        for (int kf = 0; kf < 4; ++kf) {
            const short8* wr = (const short8*)(wp + OFF_WE1 + (size_t)(kf + 6) * 8 * 512) + lane;
#pragma unroll
            for (int nf = 0; nf < 8; ++nf)
                acc[nf] = __builtin_amdgcn_mfma_f32_16x16x32_bf16(ac[kf], wr[nf * 64], acc[nf], 0, 0, 0);
        }
    }
    store_pk<8>(T1, 256, acc, w, lane);       // Y1 (packed, wave-private rows)

    // ==== edge MLP layer 2 -> EF (wave-private, no barrier) ====
    layer_gemm<4, 8>(T1, 256, wp + OFF_WE2, be2, acc, w, lane);
    store_pk<8>(T1, 256, acc, w, lane);       // EF (packed)

    // ==== coord MLP layer 1 (wave-private EF rows) ====
    f4 accC[8];
    layer_gemm<4, 8>(T1, 256, wp + OFF_WC1, bc1, accC, w, lane);

    __syncthreads();   // B2: EF tile complete
    // ==== agg: segmented reduce over sorted rows, paired u32 reads ====
    // thread: group g = tid>>6 (16 rows each); lane: j = lane>>4, c = lane&15
    // u32 at (row, bytes j*64+c*4) holds logical cols (32j+c, 32j+16+c)
    {
        const int g = tid >> 6, j = (tid >> 4) & 3, c = tid & 15;
        const int boff = j * 64 + c * 4;
        const int n0 = 32 * j + c, n1 = n0 + 16;
        const int m0 = g * 16;
        int curr = rows_s[m0];
        float s0 = 0.f, s1 = 0.f;
        for (int m = m0; m < m0 + 16; ++m) {
            int r = rows_s[m];
            unsigned vv = *(const unsigned*)((const char*)T1 + m * 256 + (boff ^ ((m & 7) << 4)));
            if (r != curr) {
                atomicAdd(&agg[(size_t)curr * HD + n0], s0);
                atomicAdd(&agg[(size_t)curr * HD + n1], s1);
                s0 = 0.f; s1 = 0.f; curr = r;
            }
            s0 += asf(vv << 16);
            s1 += asf(vv & 0xFFFF0000u);
        }
        atomicAdd(&agg[(size_t)curr * HD + n0], s0);
        atomicAdd(&agg[(size_t)curr * HD + n1], s1);
    }
    __syncthreads();   // B3: EF reads done, T1 reusable

    // ==== coord C1 -> T1 (packed), final CL layer, O22 ====
    store_pk<8>(T1, 256, accC, w, lane);
    layer_gemm<4, 2>(T1, 256, wp + OFF_WCL, (const float*)nullptr, accC, w, lane);
    float* O22 = (float*)Twd;                  // 64x32 f32 = 8 KB (wd tile dead)
    {
        const int rb = 16 * w + ((lane >> 4) << 2), cb = lane & 15;
#pragma unroll
        for (int nf = 0; nf < 2; ++nf)
#pragma unroll
            for (int r = 0; r < 4; ++r)
                O22[(rb + r) * 32 + nf * 16 + cb] = accC[nf][r];
    }
    __syncthreads();   // B4: O22 visible

    // ==== wind: segmented reduce (8 groups x 8 rows) ====
    {
        const int c = tid & 31, qq = tid >> 5;
        if (c < 22) {
            const bool isU = c < LVN;
            const int lvl = isU ? c : c - LVN;
            float* dst = isU ? aggu : aggv;
            const float* radp = isU ? radu_s : radv_s;
            const int m0 = qq * 8;
            int curr = rows_s[m0]; float s = 0.f;
            for (int m = m0; m < m0 + 8; ++m) {
                int r = rows_s[m];
                float vv = O22[m * 32 + c] * radp[m];
                if (r != curr) { atomicAdd(&dst[(size_t)curr * LVN + lvl], s); s = 0.f; curr = r; }
                s += vv;
            }
            atomicAdd(&dst[(size_t)curr * LVN + lvl], s);
        }
    }
}

// ================= post: lat-band mean | wind finalize =================
__global__ __launch_bounds__(256)
void post_kernel(const float* __restrict__ agg, short* __restrict__ latb,
                 float* __restrict__ aggu, float* __restrict__ aggv,
                 const int* __restrict__ off)
{
    const int b = blockIdx.x, tid = threadIdx.x;
    if (b < NLAT) {
        __shared__ float part[256];
        const int j = tid & 127, half = tid >> 7;
        float s = 0.f;
        for (int lon = half * 120; lon < (half + 1) * 120; ++lon)
            s += agg[((size_t)b * NLON + lon) * HD + j];
        part[tid] = s;
        __syncthreads();
        if (tid < 128)
            latb[(size_t)b * HD + tid] = f2b((part[tid] + part[128 + tid]) * (1.0f / NLON));
        return;
    }
    int tt = (b - NLAT) * 256 + tid;
    if (tt >= NN * LVN) return;
    int n = tt / LVN;
    float c = fmaxf((float)(off[n + 1] - off[n]), 1.f);
    float xu = aggu[tt] / c, xv = aggv[tt] / c;
    aggu[tt] = fminf(fmaxf(xu, -100.f), 100.f);
    aggv[tt] = fminf(fmaxf(xv, -100.f), 100.f);
}

// ================= node kernel (direct-reg A, packed T1) =================
__global__ __launch_bounds__(512, 4)
void node_mfma(const short* __restrict__ hb, const float* __restrict__ h,
               const short* __restrict__ latb,
               const float* __restrict__ bn1, const float* __restrict__ bn2,
               const short* __restrict__ wp, float* __restrict__ out)
{
    __shared__ short T1[128 * 128];
    const int tid = threadIdx.x, lane = tid & 63, w = tid >> 6;
    const int n0 = blockIdx.x * 128;
    const int mrow = 16 * w + (lane & 15);
    const int koff = 8 * (lane >> 4);
    const int n = n0 + mrow;
    const int nc = (n < NN) ? n : (NN - 1);
    const short* hp = hb + (size_t)nc * HD + koff;
    const float* ap = out + (size_t)nc * HD + koff;
    const short* lp = latb + (size_t)(nc / NLON) * HD + koff;

    f4 acc[8];
#pragma unroll
    for (int nf = 0; nf < 8; ++nf) {
        float bv = bn1[nf * 16 + (lane & 15)];
        acc[nf] = (f4){bv, bv, bv, bv};
    }
#pragma unroll
    for (int kf = 0; kf < 4; ++kf) {
        short8 a = *(const short8*)(hp + kf * 32);
        const short8* wr = (const short8*)(wp + OFF_WN1 + (size_t)kf * 8 * 512) + lane;
#pragma unroll
        for (int nf = 0; nf < 8; ++nf)
            acc[nf] = __builtin_amdgcn_mfma_f32_16x16x32_bf16(a, wr[nf * 64], acc[nf], 0, 0, 0);
    }
#pragma unroll
    for (int kf = 0; kf < 4; ++kf) {
        short8 a;
#pragma unroll
        for (int j = 0; j < 8; ++j) a[j] = f2b(ap[kf * 32 + j]);
        const short8* wr = (const short8*)(wp + OFF_WN1 + (size_t)(kf + 4) * 8 * 512) + lane;
#pragma unroll
        for (int nf = 0; nf < 8; ++nf)
            acc[nf] = __builtin_amdgcn_mfma_f32_16x16x32_bf16(a, wr[nf * 64], acc[nf], 0, 0, 0);
    }
#pragma unroll
    for (int kf = 0; kf < 4; ++kf) {
        short8 a = *(const short8*)(lp + kf * 32);
        const short8* wr = (const short8*)(wp + OFF_WN1 + (size_t)(kf + 8) * 8 * 512) + lane;
#pragma unroll
        for (int nf = 0; nf < 8; ++nf)
            acc[nf] = __builtin_amdgcn_mfma_f32_16x16x32_bf16(a, wr[nf * 64], acc[nf], 0, 0, 0);
    }
    store_pk<8>(T1, 256, acc, w, lane);       // packed; Wn2 is k-permuted to match
    layer_gemm<4, 8>(T1, 256, wp + OFF_WN2, bn2, acc, w, lane);

    const int rb = 16 * w + ((lane >> 4) << 2), cb = lane & 15;
#pragma unroll
    for (int nf = 0; nf < 8; ++nf)
#pragma unroll
        for (int r = 0; r < 4; ++r) {
            int gn = n0 + rb + r;
            if (gn < NN) {
                int colj = nf * 16 + cb;
                out[(size_t)gn * HD + colj] = acc[nf][r] + h[(size_t)gn * HD + colj];
            }
        }
}

extern "C" void kernel_launch(void* const* d_in, const int* in_sizes, int n_in,
                              void* d_out, int out_size, void* d_ws, size_t ws_size,
                              hipStream_t stream)
{
    const float* h   = (const float*)d_in[0];
    const float* u   = (const float*)d_in[1];
    const float* v   = (const float*)d_in[2];
    const float* ea  = (const float*)d_in[3];
    const float* We1 = (const float*)d_in[4];
    const float* be1 = (const float*)d_in[5];
    const float* We2 = (const float*)d_in[6];
    const float* be2 = (const float*)d_in[7];
    const float* Wn1 = (const float*)d_in[8];
    const float* bn1 = (const float*)d_in[9];
    const float* Wn2 = (const float*)d_in[10];
    const float* bn2 = (const float*)d_in[11];
    const float* Wc1 = (const float*)d_in[12];
    const float* bc1 = (const float*)d_in[13];
    const float* Wcl = (const float*)d_in[14];
    const int*   eidx = (const int*)d_in[15];

    float* out  = (float*)d_out;
    float* agg  = out;                       // [NN,HD]: agg accum, then h_out
    float* aggu = out + (size_t)NN * HD;
    float* aggv = aggu + (size_t)NN * LVN;

    // ---- workspace layout (no overlaps) ----
    char* p = (char*)d_ws;
    short* wp  = (short*)p;                  p += (size_t)WP_SHORTS * 2;
    int*   off = (int*)p;                    p += (size_t)(NN + 1) * 4;
    int*   csr = (int*)p;                    p += (size_t)EE * 4;
    p = (char*)(((size_t)p + 15) & ~(size_t)15);
    short* hb  = (short*)p;                  p += (size_t)NN * HD * 2;
    float* uvr = (float*)p;                  p += (size_t)NN * 36 * 4;
    short* latb = (short*)p;                 p += (size_t)NLAT * HD * 2;
    p = (char*)(((size_t)p + 15) & ~(size_t)15);
    int*   cnt = (int*)p;                    p += (size_t)NN * 4;
    int*   cur = (int*)p;

    hipMemsetAsync(d_out, 0, (size_t)out_size * sizeof(float), stream);
    hipMemsetAsync(cnt, 0, (size_t)2 * NN * sizeof(int), stream);

    setup_kernel<<<SB_HIST + SB_HCAST + SB_UV + SB_WP, 256, 0, stream>>>(
        eidx, cnt, h, hb, u, v, uvr, We1, We2, Wc1, Wcl, Wn1, Wn2, wp);
    scan_kernel<<<1, 1024, 0, stream>>>(cnt, off);
    scatter_kernel<<<EE / 256, 256, 0, stream>>>(eidx, off, cur, csr);

    edge_mfma<<<EE / 64, 256, 0, stream>>>(hb, uvr, ea, be1, be2, bc1,
                                           wp, eidx, csr, agg, aggu, aggv);

    post_kernel<<<NLAT + (NN * LVN + 255) / 256, 256, 0, stream>>>(
        agg, latb, aggu, aggv, off);

    node_mfma<<<(NN + 127) / 128, 512, 0, stream>>>(hb, h, latb, bn1, bn2, wp, agg);
}

// Round 9
// 339.683 us; speedup vs baseline: 5.3604x; 1.0023x over previous
//
#include <hip/hip_runtime.h>
#include <hip/hip_bf16.h>
#include <math.h>

#define NN   29040
#define NLAT 121
#define NLON 240
#define HD   128
#define LVN  11
#define EE   464640

typedef __attribute__((ext_vector_type(8))) short short8;
typedef __attribute__((ext_vector_type(4))) float f4;

// packed-weight offsets (in shorts) inside wp buffer
#define OFF_WE1 0          // 10 kf x 8 nf  = 80 frags
#define OFF_WE2 40960      // 4 x 8 = 32
#define OFF_WC1 57344      // 4 x 8 = 32
#define OFF_WCL 73728      // 4 x 2 = 8
#define OFF_WN1 77824      // 12 x 8 = 96
#define OFF_WN2 126976     // 4 x 8 = 32
#define WP_SHORTS 143360

__device__ inline short f2b(float x) {
    union { __hip_bfloat16 b; short s; } v;
    v.b = __float2bfloat16(x);
    return v.s;
}
__device__ inline float b2f(unsigned short b) {
    union { unsigned u; float f; } v; v.u = ((unsigned)b) << 16;
    return v.f;
}
__device__ inline unsigned pk2(float lo, float hi) {
    return ((unsigned)(unsigned short)f2b(hi) << 16) | (unsigned short)f2b(lo);
}
__device__ inline float asf(unsigned u) {
    union { unsigned u; float f; } v; v.u = u;
    return v.f;
}

// ================= fused setup: hist | h-cast | uv-prep | weight-pack =================
#define SB_HIST  1815
#define SB_HCAST 1815
#define SB_UV    114
#define SB_WP    70

__global__ __launch_bounds__(256)
void setup_kernel(const int* __restrict__ eidx, int* __restrict__ cnt,
                  const float* __restrict__ h, short* __restrict__ hb,
                  const float* __restrict__ u, const float* __restrict__ v,
                  float* __restrict__ uvrec,
                  const float* __restrict__ We1, const float* __restrict__ We2,
                  const float* __restrict__ Wc1, const float* __restrict__ Wcl,
                  const float* __restrict__ Wn1, const float* __restrict__ Wn2,
                  short* __restrict__ wp)
{
    const int b = blockIdx.x, tid = threadIdx.x;
    if (b < SB_HIST) {
        int e = b * 256 + tid;
        atomicAdd(&cnt[eidx[e]], 1);
        return;
    }
    if (b < SB_HIST + SB_HCAST) {
        int idx = (b - SB_HIST) * 256 + tid;          // 8 elems each
        const float4* hf = (const float4*)h;
        float4 a = hf[idx * 2], c = hf[idx * 2 + 1];
        short8 o;
        o[0] = f2b(a.x); o[1] = f2b(a.y); o[2] = f2b(a.z); o[3] = f2b(a.w);
        o[4] = f2b(c.x); o[5] = f2b(c.y); o[6] = f2b(c.z); o[7] = f2b(c.w);
        ((short8*)hb)[idx] = o;
        return;
    }
    if (b < SB_HIST + SB_HCAST + SB_UV) {
        int n = (b - SB_HIST - SB_HCAST) * 256 + tid;
        if (n >= NN) return;
        float* r = uvrec + (size_t)n * 36;
        float un = 0.f, vn = 0.f;
#pragma unroll
        for (int l = 0; l < LVN; ++l) {
            float uu = u[n * LVN + l], vv = v[n * LVN + l];
            float s = sqrtf(uu * uu + vv * vv);
            r[l]      = uu / s;
            r[11 + l] = vv / s;
            r[22 + l] = s;
            un += uu * uu; vn += vv * vv;
        }
        r[33] = sqrtf(un);
        r[34] = sqrtf(vn);
        r[35] = 0.f;
        return;
    }
    // weight pack: 4 fragments per block.
    // kinds {1,2,3,5} consume PACKED tiles -> k-permuted fragment order:
    //   k = kf*32 + (i&1)*16 + 4*(l>>4) + (i>>1)
    // kinds {0,4} consume unpacked data -> k = kf*32 + 8*(l>>4) + i
    {
        int fg = (b - SB_HIST - SB_HCAST - SB_UV) * 4 + (tid >> 6);   // 0..279
        const int l = tid & 63;
        int kind, f, base;
        if (fg < 80)       { kind = 0; f = fg;       base = OFF_WE1; }
        else if (fg < 112) { kind = 1; f = fg - 80;  base = OFF_WE2; }
        else if (fg < 144) { kind = 2; f = fg - 112; base = OFF_WC1; }
        else if (fg < 152) { kind = 3; f = fg - 144; base = OFF_WCL; }
        else if (fg < 248) { kind = 4; f = fg - 152; base = OFF_WN1; }
        else               { kind = 5; f = fg - 248; base = OFF_WN2; }
        const int nfw = (kind == 3) ? 2 : 8;
        const int kf = f / nfw, nf = f % nfw;
        const bool perm = (kind == 1) || (kind == 2) || (kind == 3) || (kind == 5);
        short* dst = wp + base + (size_t)f * 512 + l * 8;
        const int hgrp = l >> 4;
        for (int i = 0; i < 8; ++i) {
            int k = perm ? (kf * 32 + ((i & 1) << 4) + (hgrp << 2) + (i >> 1))
                         : (kf * 32 + (hgrp << 3) + i);
            int n = nf * 16 + (l & 15);
            float val = 0.f;
            if (kind == 0) {
                int r = (k < 33) ? (256 + k) : (k == 33 ? 289 : (k < 64 ? -1 : k - 64));
                if (r >= 0) val = We1[r * HD + n];
            } else if (kind == 1) val = We2[k * HD + n];
            else if (kind == 2)  val = Wc1[k * HD + n];
            else if (kind == 3)  { if (n < 22) val = Wcl[k * 22 + n]; }
            else if (kind == 4)  val = Wn1[k * HD + n];
            else                 val = Wn2[k * HD + n];
            dst[i] = f2b(val);
        }
    }
}

// ================= CSR scan + scatter =================
__global__ __launch_bounds__(1024)
void scan_kernel(const int* __restrict__ cnt, int* __restrict__ off)
{
    __shared__ int part[1024];
    const int tid = threadIdx.x;
    const int CH = 29;
    int lo = tid * CH, hi = min(lo + CH, NN);
    int s = 0;
    for (int i = lo; i < hi; ++i) s += cnt[i];
    part[tid] = s;
    __syncthreads();
    for (int d = 1; d < 1024; d <<= 1) {
        int vv = (tid >= d) ? part[tid - d] : 0;
        __syncthreads();
        part[tid] += vv;
        __syncthreads();
    }
    int run = (tid == 0) ? 0 : part[tid - 1];
    for (int i = lo; i < hi; ++i) { off[i] = run; run += cnt[i]; }
    if (tid == 1023) off[NN] = run;
}

__global__ __launch_bounds__(256)
void scatter_kernel(const int* __restrict__ eidx, const int* __restrict__ off,
                    int* __restrict__ cur, int* __restrict__ csr)
{
    int e = blockIdx.x * 256 + threadIdx.x;
    if (e >= EE) return;
    int row = eidx[e];
    int p = atomicAdd(&cur[row], 1);
    csr[off[row] + p] = e;
}

// ================= GEMM helpers =================
template<int KF, int NF>
__device__ inline void layer_gemm(const short* At, int rs, const short* Wp,
                                  const float* bias, f4* acc, int w, int lane)
{
    const int m = 16 * w + (lane & 15);
    const char* arow = (const char*)At + m * rs;
    const int sw = (m & 7) << 4;
    const int kb = (lane >> 4) << 4;
#pragma unroll
    for (int nf = 0; nf < NF; ++nf) {
        float bv = bias ? bias[nf * 16 + (lane & 15)] : 0.f;
        acc[nf] = (f4){bv, bv, bv, bv};
    }
#pragma unroll
    for (int kf = 0; kf < KF; ++kf) {
        short8 a = *(const short8*)(arow + ((kf * 64 + kb) ^ sw));
        const short8* wr = (const short8*)(Wp + (size_t)kf * NF * 512) + lane;
#pragma unroll
        for (int nf = 0; nf < NF; ++nf) {
            short8 bfr = wr[nf * 64];
            acc[nf] = __builtin_amdgcn_mfma_f32_16x16x32_bf16(a, bfr, acc[nf], 0, 0, 0);
        }
    }
}

// packed store: column pairs (2j,2j+1) -> one u32 (lo=2j, hi=2j+1), relu applied.
template<int NF>
__device__ inline void store_pk(short* tile, int rs, const f4* acc, int w, int lane)
{
    const int rb = 16 * w + ((lane >> 4) << 2);
    const int cb = (lane & 15) * 4;
#pragma unroll
    for (int j = 0; j < NF / 2; ++j)
#pragma unroll
        for (int r = 0; r < 4; ++r) {
            int row = rb + r;
            float lo = fmaxf(acc[2 * j][r], 0.f);
            float hi = fmaxf(acc[2 * j + 1][r], 0.f);
            *(unsigned*)((char*)tile + row * rs + ((j * 64 + cb) ^ ((row & 7) << 4))) = pk2(lo, hi);
        }
}

// ================= edge kernel: 64-edge tiles, 4 independent waves, ZERO barriers =================
// Every phase is wave-private: wd build (lanes 4i+q cover own 16 rows), GEMM chain
// (own rows of T1), agg/wind reduce (group = wave reads its own rows). Same-wave
// LDS write->read ordering is guaranteed (in-order DS + compiler lgkmcnt waits).
// Waves drift freely -> one wave's gather latency hides under another's MFMA,
// which the round-8 lockstep-barrier structure prevented (60% no-issue cycles).
__global__ __launch_bounds__(256, 4)
void edge_mfma(const short* __restrict__ hb, const float* __restrict__ uvrec,
               const float* __restrict__ ea,
               const float* __restrict__ be1, const float* __restrict__ be2,
               const float* __restrict__ bc1,
               const short* __restrict__ wp,
               const int* __restrict__ eidx, const int* __restrict__ csr,
               float* __restrict__ agg, float* __restrict__ aggu,
               float* __restrict__ aggv)
{
    __shared__ short Twd[64 * 64];     // 8 KB wd tile (128B rows); later O22 f32
    __shared__ short T1[64 * 128];     // 16 KB (256B rows), packed layout
    __shared__ int   rows_s[64];
    __shared__ float radu_s[64], radv_s[64];

    const int tid = threadIdx.x, lane = tid & 63, w = tid >> 6;   // w in 0..3
    const int e0 = blockIdx.x * 64;
    const int mrow = 16 * w + (lane & 15);       // 0..63
    const int koff = 8 * (lane >> 4);
    const int sw   = (mrow & 7) << 4;

    // ---- own-row index chain + EARLY h fragment gather ----
    int e1 = csr[e0 + mrow];
    int rowm = eidx[e1], colm = eidx[EE + e1];
    short8 ar[4], ac[4];
    {
        const short* hr = hb + (size_t)rowm * HD + koff;
        const short* hc = hb + (size_t)colm * HD + koff;
#pragma unroll
        for (int kf = 0; kf < 4; ++kf) {
            ar[kf] = *(const short8*)(hr + kf * 32);
            ac[kf] = *(const short8*)(hc + kf * 32);
        }
    }

    // ---- wd tile build: WAVE-PRIVATE rows (lane>>2 within own 16-row slice) ----
    {
        const int m2 = 16 * w + (lane >> 2), q = lane & 3;
        const int sw2 = (m2 & 7) << 4;
        int e2 = csr[e0 + m2];
        int row2 = eidx[e2], col2 = eidx[EE + e2];
        const float* rc = uvrec + (size_t)col2 * 36;
        const float* rr = uvrec + (size_t)row2 * 36;
        char* arow = (char*)(Twd + m2 * 64);
        short8 z = {0, 0, 0, 0, 0, 0, 0, 0};
        *(short8*)(arow + q * 32) = z;
        *(short8*)(arow + q * 32 + 16) = z;
        for (int l = q; l < LVN; l += 4) {
            float rel = rc[l] * rr[l] + rc[11 + l] * rr[11 + l];
            *(short*)(arow + ((2 * l) ^ sw2))        = f2b(rel);
            *(short*)(arow + ((2 * (11 + l)) ^ sw2)) = f2b(rc[22 + l]);
            *(short*)(arow + ((2 * (22 + l)) ^ sw2)) = f2b(rr[22 + l]);
        }
        if (q == 0) { rows_s[m2] = row2; radu_s[m2] = rc[33]; radv_s[m2] = rc[34]; }
        if (q == 3) *(short*)(arow + ((2 * 33) ^ sw2)) = f2b(ea[e2]);
    }
    // no barrier: all consumers below read only this wave's rows

    // ==== edge MLP layer 1 ====
    f4 acc[8];
#pragma unroll
    for (int nf = 0; nf < 8; ++nf) {
        float bv = be1[nf * 16 + (lane & 15)];
        acc[nf] = (f4){bv, bv, bv, bv};
    }
    {
        const char* awd = (const char*)(Twd + mrow * 64);
#pragma unroll
        for (int kf = 0; kf < 2; ++kf) {
            short8 a = *(const short8*)(awd + ((kf * 64 + 2 * koff) ^ sw));
            const short8* wr = (const short8*)(wp + OFF_WE1 + (size_t)kf * 8 * 512) + lane;
#pragma unroll
            for (int nf = 0; nf < 8; ++nf)
                acc[nf] = __builtin_amdgcn_mfma_f32_16x16x32_bf16(a, wr[nf * 64], acc[nf], 0, 0, 0);
        }
#pragma unroll
        for (int kf = 0; kf < 4; ++kf) {
            const short8* wr = (const short8*)(wp + OFF_WE1 + (size_t)(kf + 2) * 8 * 512) + lane;
#pragma unroll
            for (int nf = 0; nf < 8; ++nf)
                acc[nf] = __builtin_amdgcn_mfma_f32_16x16x32_bf16(ar[kf], wr[nf * 64], acc[nf], 0, 0, 0);
        }
#pragma unroll
        for (int kf = 0; kf < 4; ++kf) {
            const short8* wr = (const short8*)(wp + OFF_WE1 + (size_t)(kf + 6) * 8 * 512) + lane;
#pragma unroll
            for (int nf = 0; nf < 8; ++nf)
                acc[nf] = __builtin_amdgcn_mfma_f32_16x16x32_bf16(ac[kf], wr[nf * 64], acc[nf], 0, 0, 0);
        }
    }
    store_pk<8>(T1, 256, acc, w, lane);       // Y1 (packed, wave-private rows)

    // ==== edge MLP layer 2 -> EF (wave-private) ====
    layer_gemm<4, 8>(T1, 256, wp + OFF_WE2, be2, acc, w, lane);
    store_pk<8>(T1, 256, acc, w, lane);       // EF (packed)

    // ==== coord MLP layer 1 (wave-private EF rows) ====
    f4 accC[8];
    layer_gemm<4, 8>(T1, 256, wp + OFF_WC1, bc1, accC, w, lane);

    // ==== agg: segmented reduce over sorted rows (own wave's 16 rows) ====
    {
        const int g = w, j = (lane >> 4) & 3, c = lane & 15;
        const int boff = j * 64 + c * 4;
        const int n0 = 32 * j + c, n1 = n0 + 16;
        const int m0 = g * 16;
        int curr = rows_s[m0];
        float s0 = 0.f, s1 = 0.f;
        for (int m = m0; m < m0 + 16; ++m) {
            int r = rows_s[m];
            unsigned vv = *(const unsigned*)((const char*)T1 + m * 256 + (boff ^ ((m & 7) << 4)));
            if (r != curr) {
                atomicAdd(&agg[(size_t)curr * HD + n0], s0);
                atomicAdd(&agg[(size_t)curr * HD + n1], s1);
                s0 = 0.f; s1 = 0.f; curr = r;
            }
            s0 += asf(vv << 16);
            s1 += asf(vv & 0xFFFF0000u);
        }
        atomicAdd(&agg[(size_t)curr * HD + n0], s0);
        atomicAdd(&agg[(size_t)curr * HD + n1], s1);
    }

    // ==== coord C1 -> T1 (packed, own rows; EF reads above are done in-wave) ====
    store_pk<8>(T1, 256, accC, w, lane);
    layer_gemm<4, 2>(T1, 256, wp + OFF_WCL, (const float*)nullptr, accC, w, lane);
    float* O22 = (float*)Twd;                  // 64x32 f32 overlay (own rows only)
    {
        const int rb = 16 * w + ((lane >> 4) << 2), cb = lane & 15;
#pragma unroll
        for (int nf = 0; nf < 2; ++nf)
#pragma unroll
            for (int r = 0; r < 4; ++r)
                O22[(rb + r) * 32 + nf * 16 + cb] = accC[nf][r];
    }

    // ==== wind: segmented reduce (2 groups x 8 rows per wave, own rows) ====
    {
        const int c = lane & 31, qq = 2 * w + (lane >> 5);
        if (c < 22) {
            const bool isU = c < LVN;
            const int lvl = isU ? c : c - LVN;
            float* dst = isU ? aggu : aggv;
            const float* radp = isU ? radu_s : radv_s;
            const int m0 = qq * 8;
            int curr = rows_s[m0]; float s = 0.f;
            for (int m = m0; m < m0 + 8; ++m) {
                int r = rows_s[m];
                float vv = O22[m * 32 + c] * radp[m];
                if (r != curr) { atomicAdd(&dst[(size_t)curr * LVN + lvl], s); s = 0.f; curr = r; }
                s += vv;
            }
            atomicAdd(&dst[(size_t)curr * LVN + lvl], s);
        }
    }
}

// ================= post: lat-band mean | wind finalize =================
__global__ __launch_bounds__(256)
void post_kernel(const float* __restrict__ agg, short* __restrict__ latb,
                 float* __restrict__ aggu, float* __restrict__ aggv,
                 const int* __restrict__ off)
{
    const int b = blockIdx.x, tid = threadIdx.x;
    if (b < NLAT) {
        __shared__ float part[256];
        const int j = tid & 127, half = tid >> 7;
        float s = 0.f;
        for (int lon = half * 120; lon < (half + 1) * 120; ++lon)
            s += agg[((size_t)b * NLON + lon) * HD + j];
        part[tid] = s;
        __syncthreads();
        if (tid < 128)
            latb[(size_t)b * HD + tid] = f2b((part[tid] + part[128 + tid]) * (1.0f / NLON));
        return;
    }
    int tt = (b - NLAT) * 256 + tid;
    if (tt >= NN * LVN) return;
    int n = tt / LVN;
    float c = fmaxf((float)(off[n + 1] - off[n]), 1.f);
    float xu = aggu[tt] / c, xv = aggv[tt] / c;
    aggu[tt] = fminf(fmaxf(xu, -100.f), 100.f);
    aggv[tt] = fminf(fmaxf(xv, -100.f), 100.f);
}

// ================= node kernel (direct-reg A, packed T1) =================
__global__ __launch_bounds__(512, 4)
void node_mfma(const short* __restrict__ hb, const float* __restrict__ h,
               const short* __restrict__ latb,
               const float* __restrict__ bn1, const float* __restrict__ bn2,
               const short* __restrict__ wp, float* __restrict__ out)
{
    __shared__ short T1[128 * 128];
    const int tid = threadIdx.x, lane = tid & 63, w = tid >> 6;
    const int n0 = blockIdx.x * 128;
    const int mrow = 16 * w + (lane & 15);
    const int koff = 8 * (lane >> 4);
    const int n = n0 + mrow;
    const int nc = (n < NN) ? n : (NN - 1);
    const short* hp = hb + (size_t)nc * HD + koff;
    const float* ap = out + (size_t)nc * HD + koff;
    const short* lp = latb + (size_t)(nc / NLON) * HD + koff;

    f4 acc[8];
#pragma unroll
    for (int nf = 0; nf < 8; ++nf) {
        float bv = bn1[nf * 16 + (lane & 15)];
        acc[nf] = (f4){bv, bv, bv, bv};
    }
#pragma unroll
    for (int kf = 0; kf < 4; ++kf) {
        short8 a = *(const short8*)(hp + kf * 32);
        const short8* wr = (const short8*)(wp + OFF_WN1 + (size_t)kf * 8 * 512) + lane;
#pragma unroll
        for (int nf = 0; nf < 8; ++nf)
            acc[nf] = __builtin_amdgcn_mfma_f32_16x16x32_bf16(a, wr[nf * 64], acc[nf], 0, 0, 0);
    }
#pragma unroll
    for (int kf = 0; kf < 4; ++kf) {
        short8 a;
#pragma unroll
        for (int j = 0; j < 8; ++j) a[j] = f2b(ap[kf * 32 + j]);
        const short8* wr = (const short8*)(wp + OFF_WN1 + (size_t)(kf + 4) * 8 * 512) + lane;
#pragma unroll
        for (int nf = 0; nf < 8; ++nf)
            acc[nf] = __builtin_amdgcn_mfma_f32_16x16x32_bf16(a, wr[nf * 64], acc[nf], 0, 0, 0);
    }
#pragma unroll
    for (int kf = 0; kf < 4; ++kf) {
        short8 a = *(const short8*)(lp + kf * 32);
        const short8* wr = (const short8*)(wp + OFF_WN1 + (size_t)(kf + 8) * 8 * 512) + lane;
#pragma unroll
        for (int nf = 0; nf < 8; ++nf)
            acc[nf] = __builtin_amdgcn_mfma_f32_16x16x32_bf16(a, wr[nf * 64], acc[nf], 0, 0, 0);
    }
    store_pk<8>(T1, 256, acc, w, lane);       // packed; Wn2 is k-permuted to match
    layer_gemm<4, 8>(T1, 256, wp + OFF_WN2, bn2, acc, w, lane);

    const int rb = 16 * w + ((lane >> 4) << 2), cb = lane & 15;
#pragma unroll
    for (int nf = 0; nf < 8; ++nf)
#pragma unroll
        for (int r = 0; r < 4; ++r) {
            int gn = n0 + rb + r;
            if (gn < NN) {
                int colj = nf * 16 + cb;
                out[(size_t)gn * HD + colj] = acc[nf][r] + h[(size_t)gn * HD + colj];
            }
        }
}

extern "C" void kernel_launch(void* const* d_in, const int* in_sizes, int n_in,
                              void* d_out, int out_size, void* d_ws, size_t ws_size,
                              hipStream_t stream)
{
    const float* h   = (const float*)d_in[0];
    const float* u   = (const float*)d_in[1];
    const float* v   = (const float*)d_in[2];
    const float* ea  = (const float*)d_in[3];
    const float* We1 = (const float*)d_in[4];
    const float* be1 = (const float*)d_in[5];
    const float* We2 = (const float*)d_in[6];
    const float* be2 = (const float*)d_in[7];
    const float* Wn1 = (const float*)d_in[8];
    const float* bn1 = (const float*)d_in[9];
    const float* Wn2 = (const float*)d_in[10];
    const float* bn2 = (const float*)d_in[11];
    const float* Wc1 = (const float*)d_in[12];
    const float* bc1 = (const float*)d_in[13];
    const float* Wcl = (const float*)d_in[14];
    const int*   eidx = (const int*)d_in[15];

    float* out  = (float*)d_out;
    float* agg  = out;                       // [NN,HD]: agg accum, then h_out
    float* aggu = out + (size_t)NN * HD;
    float* aggv = aggu + (size_t)NN * LVN;

    // ---- workspace layout (no overlaps) ----
    char* p = (char*)d_ws;
    short* wp  = (short*)p;                  p += (size_t)WP_SHORTS * 2;
    int*   off = (int*)p;                    p += (size_t)(NN + 1) * 4;
    int*   csr = (int*)p;                    p += (size_t)EE * 4;
    p = (char*)(((size_t)p + 15) & ~(size_t)15);
    short* hb  = (short*)p;                  p += (size_t)NN * HD * 2;
    float* uvr = (float*)p;                  p += (size_t)NN * 36 * 4;
    short* latb = (short*)p;                 p += (size_t)NLAT * HD * 2;
    p = (char*)(((size_t)p + 15) & ~(size_t)15);
    int*   cnt = (int*)p;                    p += (size_t)NN * 4;
    int*   cur = (int*)p;

    hipMemsetAsync(d_out, 0, (size_t)out_size * sizeof(float), stream);
    hipMemsetAsync(cnt, 0, (size_t)2 * NN * sizeof(int), stream);

    setup_kernel<<<SB_HIST + SB_HCAST + SB_UV + SB_WP, 256, 0, stream>>>(
        eidx, cnt, h, hb, u, v, uvr, We1, We2, Wc1, Wcl, Wn1, Wn2, wp);
    scan_kernel<<<1, 1024, 0, stream>>>(cnt, off);
    scatter_kernel<<<EE / 256, 256, 0, stream>>>(eidx, off, cur, csr);

    edge_mfma<<<EE / 64, 256, 0, stream>>>(hb, uvr, ea, be1, be2, bc1,
                                           wp, eidx, csr, agg, aggu, aggv);

    post_kernel<<<NLAT + (NN * LVN + 255) / 256, 256, 0, stream>>>(
        agg, latb, aggu, aggv, off);

    node_mfma<<<(NN + 127) / 128, 512, 0, stream>>>(hb, h, latb, bn1, bn2, wp, agg);
}

// Round 10
// 294.577 us; speedup vs baseline: 6.1812x; 1.1531x over previous
//
#include <hip/hip_runtime.h>
#include <hip/hip_bf16.h>
#include <math.h>

#define NN   29040
#define NLAT 121
#define NLON 240
#define HD   128
#define LVN  11
#define EE   464640

typedef __attribute__((ext_vector_type(8))) short short8;
typedef __attribute__((ext_vector_type(16))) float f16v;

// packed-weight offsets (in shorts) inside wp buffer (sizes unchanged from r7)
#define OFF_WE1 0          // 20 kf x 4 nf  = 80 frags (1 KB each)
#define OFF_WE2 40960      // 8 x 4 = 32
#define OFF_WC1 57344      // 8 x 4 = 32
#define OFF_WCL 73728      // 8 x 1 = 8
#define OFF_WN1 77824      // 24 x 4 = 96
#define OFF_WN2 126976     // 8 x 4 = 32
#define WP_SHORTS 143360

__device__ inline short f2b(float x) {
    union { __hip_bfloat16 b; short s; } v;
    v.b = __float2bfloat16(x);
    return v.s;
}
__device__ inline float b2f(unsigned short b) {
    union { unsigned u; float f; } v; v.u = ((unsigned)b) << 16;
    return v.f;
}

// ================= fused setup: hist | h-cast | uv-prep | weight-pack =================
#define SB_HIST  1815
#define SB_HCAST 1815
#define SB_UV    114
#define SB_WP    70

__global__ __launch_bounds__(256)
void setup_kernel(const int* __restrict__ eidx, int* __restrict__ cnt,
                  const float* __restrict__ h, short* __restrict__ hb,
                  const float* __restrict__ u, const float* __restrict__ v,
                  float* __restrict__ uvrec,
                  const float* __restrict__ We1, const float* __restrict__ We2,
                  const float* __restrict__ Wc1, const float* __restrict__ Wcl,
                  const float* __restrict__ Wn1, const float* __restrict__ Wn2,
                  short* __restrict__ wp)
{
    const int b = blockIdx.x, tid = threadIdx.x;
    if (b < SB_HIST) {
        int e = b * 256 + tid;
        atomicAdd(&cnt[eidx[e]], 1);
        return;
    }
    if (b < SB_HIST + SB_HCAST) {
        int idx = (b - SB_HIST) * 256 + tid;          // 8 elems each
        const float4* hf = (const float4*)h;
        float4 a = hf[idx * 2], c = hf[idx * 2 + 1];
        short8 o;
        o[0] = f2b(a.x); o[1] = f2b(a.y); o[2] = f2b(a.z); o[3] = f2b(a.w);
        o[4] = f2b(c.x); o[5] = f2b(c.y); o[6] = f2b(c.z); o[7] = f2b(c.w);
        ((short8*)hb)[idx] = o;
        return;
    }
    if (b < SB_HIST + SB_HCAST + SB_UV) {
        int n = (b - SB_HIST - SB_HCAST) * 256 + tid;
        if (n >= NN) return;
        float* r = uvrec + (size_t)n * 36;
        float un = 0.f, vn = 0.f;
#pragma unroll
        for (int l = 0; l < LVN; ++l) {
            float uu = u[n * LVN + l], vv = v[n * LVN + l];
            float s = sqrtf(uu * uu + vv * vv);
            r[l]      = uu / s;
            r[11 + l] = vv / s;
            r[22 + l] = s;
            un += uu * uu; vn += vv * vv;
        }
        r[33] = sqrtf(un);
        r[34] = sqrtf(vn);
        r[35] = 0.f;
        return;
    }
    // ---- weight pack for 32x32x16 MFMA B-fragments ----
    // lane l, elem i -> k = kf*16 + 8*(l>>5) + i ; n = nf*32 + (l&31)
    {
        int fg = (b - SB_HIST - SB_HCAST - SB_UV) * 4 + (tid >> 6);   // 0..279
        const int l = tid & 63;
        int kind, f, base;
        if (fg < 80)       { kind = 0; f = fg;       base = OFF_WE1; }   // 20x4
        else if (fg < 112) { kind = 1; f = fg - 80;  base = OFF_WE2; }   // 8x4
        else if (fg < 144) { kind = 2; f = fg - 112; base = OFF_WC1; }   // 8x4
        else if (fg < 152) { kind = 3; f = fg - 144; base = OFF_WCL; }   // 8x1
        else if (fg < 248) { kind = 4; f = fg - 152; base = OFF_WN1; }   // 24x4
        else               { kind = 5; f = fg - 248; base = OFF_WN2; }   // 8x4
        const int nfw = (kind == 3) ? 1 : 4;
        const int kf = f / nfw, nf = f % nfw;
        short* dst = wp + base + (size_t)f * 512 + l * 8;
        for (int i = 0; i < 8; ++i) {
            int k = kf * 16 + ((l >> 5) << 3) + i;
            int n = nf * 32 + (l & 31);
            float val = 0.f;
            if (kind == 0) {
                // A cols: 0..33 wd|ea -> We1 rows 256..289; 34..63 pad; 64.. -> rows k-64
                int r = (k < 33) ? (256 + k) : (k == 33 ? 289 : (k < 64 ? -1 : k - 64));
                if (r >= 0) val = We1[r * HD + n];
            } else if (kind == 1) val = We2[k * HD + n];
            else if (kind == 2)  val = Wc1[k * HD + n];
            else if (kind == 3)  { if (n < 22) val = Wcl[k * 22 + n]; }
            else if (kind == 4)  val = Wn1[k * HD + n];
            else                 val = Wn2[k * HD + n];
            dst[i] = f2b(val);
        }
    }
}

// ================= CSR scan + scatter =================
__global__ __launch_bounds__(1024)
void scan_kernel(const int* __restrict__ cnt, int* __restrict__ off)
{
    __shared__ int part[1024];
    const int tid = threadIdx.x;
    const int CH = 29;
    int lo = tid * CH, hi = min(lo + CH, NN);
    int s = 0;
    for (int i = lo; i < hi; ++i) s += cnt[i];
    part[tid] = s;
    __syncthreads();
    for (int d = 1; d < 1024; d <<= 1) {
        int vv = (tid >= d) ? part[tid - d] : 0;
        __syncthreads();
        part[tid] += vv;
        __syncthreads();
    }
    int run = (tid == 0) ? 0 : part[tid - 1];
    for (int i = lo; i < hi; ++i) { off[i] = run; run += cnt[i]; }
    if (tid == 1023) off[NN] = run;
}

__global__ __launch_bounds__(256)
void scatter_kernel(const int* __restrict__ eidx, const int* __restrict__ off,
                    int* __restrict__ cur, int* __restrict__ csr)
{
    int e = blockIdx.x * 256 + threadIdx.x;
    if (e >= EE) return;
    int row = eidx[e];
    int p = atomicAdd(&cur[row], 1);
    csr[off[row] + p] = e;
}

// ================= 32x32x16 GEMM helpers =================
// A row = mrow (lane&31 within row-group), k = kf*16 + 8*kh + i.
// C: col = lane&31, row = (reg&3) + 8*(reg>>2) + 4*kh   [HW-verified m74/m101]
template<int KF, int NFL, int NJ>
__device__ inline void gemm32_lds(const short* At, const short* Wp, int nf0,
                                  const float* bias, f16v* acc,
                                  int mrow, int colbase, int r31, int kh, int lane)
{
    const char* arow = (const char*)At + mrow * 256;
    const int sw = (mrow & 7) << 4;
#pragma unroll
    for (int j = 0; j < NJ; ++j) {
        float bv = bias ? bias[colbase + j * 32 + r31] : 0.f;
#pragma unroll
        for (int q = 0; q < 16; ++q) acc[j][q] = bv;
    }
#pragma unroll
    for (int kf = 0; kf < KF; ++kf) {
        short8 a = *(const short8*)(arow + ((kf * 32 + 16 * kh) ^ sw));
#pragma unroll
        for (int j = 0; j < NJ; ++j) {
            short8 bfr = *(const short8*)(Wp + (size_t)(kf * NFL + nf0 + j) * 512 + lane * 8);
            acc[j] = __builtin_amdgcn_mfma_f32_32x32x16_bf16(a, bfr, acc[j], 0, 0, 0);
        }
    }
}

// store C (optionally relu) as bf16 row-major tile, 256B rows, XOR-swizzled
template<int NJ>
__device__ inline void store32(short* tile, const f16v* acc, int rg, int colbase,
                               int r31, int kh, bool relu)
{
#pragma unroll
    for (int j = 0; j < NJ; ++j)
#pragma unroll
        for (int reg = 0; reg < 16; ++reg) {
            int row = rg * 32 + (reg & 3) + 8 * (reg >> 2) + 4 * kh;
            int cb2 = (colbase + j * 32 + r31) * 2;
            float vv = acc[j][reg];
            if (relu) vv = fmaxf(vv, 0.f);
            *(short*)((char*)tile + row * 256 + (cb2 ^ ((row & 7) << 4))) = f2b(vv);
        }
}

// ================= edge kernel: 64-edge tiles, 32x32x16 MFMA =================
// Wave w: rg=w>>1 (rows 32rg..+31), cg=w&1 (cols 64cg..+63 = 2 B-frags).
// Each 16B B-fragment now covers 32 cols x K=16 and feeds 32 rows -> per-edge
// weight-L1 traffic halved vs 16x16x32 (the r9-diagnosed bottleneck: warm-cache
// FETCH 42MB at identical duration => on-chip L1 weight streaming bound).
__global__ __launch_bounds__(256, 4)
void edge_mfma(const short* __restrict__ hb, const float* __restrict__ uvrec,
               const float* __restrict__ ea,
               const float* __restrict__ be1, const float* __restrict__ be2,
               const float* __restrict__ bc1,
               const short* __restrict__ wp,
               const int* __restrict__ eidx, const int* __restrict__ csr,
               float* __restrict__ agg, float* __restrict__ aggu,
               float* __restrict__ aggv)
{
    __shared__ short Twd[64 * 64];     // 8 KB wd tile (128B rows); later O22 f32 overlay
    __shared__ short T1[64 * 128];     // 16 KB tile (256B rows)
    __shared__ int   rows_s[64];
    __shared__ float radu_s[64], radv_s[64];

    const int tid = threadIdx.x, lane = tid & 63, w = tid >> 6;
    const int rg = w >> 1, cg = w & 1;
    const int e0 = blockIdx.x * 64;
    const int r31 = lane & 31, kh = lane >> 5;
    const int mrow = rg * 32 + r31;
    const int sw = (mrow & 7) << 4;
    const int colbase = cg * 64;

    // own-row gather pointers (early issue; csr->eidx chain overlaps wd build)
    int e1 = csr[e0 + mrow];
    int rowm = eidx[e1], colm = eidx[EE + e1];
    const short* hr = hb + (size_t)rowm * HD + 8 * kh;
    const short* hc = hb + (size_t)colm * HD + 8 * kh;

    // ---- wd tile build (block-wide, 4 threads per row) ----
    {
        const int m2 = tid >> 2, q = tid & 3;
        const int sw2 = (m2 & 7) << 4;
        int e2 = csr[e0 + m2];
        int row2 = eidx[e2], col2 = eidx[EE + e2];
        const float* rc = uvrec + (size_t)col2 * 36;
        const float* rr = uvrec + (size_t)row2 * 36;
        char* arow = (char*)(Twd + m2 * 64);
        short8 z = {0, 0, 0, 0, 0, 0, 0, 0};
        *(short8*)(arow + q * 32) = z;
        *(short8*)(arow + q * 32 + 16) = z;
        for (int l = q; l < LVN; l += 4) {
            float rel = rc[l] * rr[l] + rc[11 + l] * rr[11 + l];
            *(short*)(arow + ((2 * l) ^ sw2))        = f2b(rel);
            *(short*)(arow + ((2 * (11 + l)) ^ sw2)) = f2b(rc[22 + l]);
            *(short*)(arow + ((2 * (22 + l)) ^ sw2)) = f2b(rr[22 + l]);
        }
        if (q == 0) { rows_s[m2] = row2; radu_s[m2] = rc[33]; radv_s[m2] = rc[34]; }
        if (q == 3) *(short*)(arow + ((2 * 33) ^ sw2)) = f2b(ea[e2]);
    }
    __syncthreads();   // B1: Twd/rows_s/rad visible

    // ==== edge MLP layer 1: A = [wd(k 0..63) | h_row(64..191) | h_col(192..319)] ====
    f16v acc[2];
#pragma unroll
    for (int j = 0; j < 2; ++j) {
        float bv = be1[colbase + j * 32 + r31];
#pragma unroll
        for (int q = 0; q < 16; ++q) acc[j][q] = bv;
    }
    {
        const char* awd = (const char*)(Twd + mrow * 64);
#pragma unroll
        for (int kf = 0; kf < 4; ++kf) {
            short8 a = *(const short8*)(awd + ((kf * 32 + 16 * kh) ^ sw));
#pragma unroll
            for (int j = 0; j < 2; ++j) {
                short8 bfr = *(const short8*)(wp + OFF_WE1 + (size_t)(kf * 4 + cg * 2 + j) * 512 + lane * 8);
                acc[j] = __builtin_amdgcn_mfma_f32_32x32x16_bf16(a, bfr, acc[j], 0, 0, 0);
            }
        }
#pragma unroll
        for (int s = 0; s < 8; ++s) {
            short8 a = *(const short8*)(hr + s * 16);
#pragma unroll
            for (int j = 0; j < 2; ++j) {
                short8 bfr = *(const short8*)(wp + OFF_WE1 + (size_t)((s + 4) * 4 + cg * 2 + j) * 512 + lane * 8);
                acc[j] = __builtin_amdgcn_mfma_f32_32x32x16_bf16(a, bfr, acc[j], 0, 0, 0);
            }
        }
#pragma unroll
        for (int s = 0; s < 8; ++s) {
            short8 a = *(const short8*)(hc + s * 16);
#pragma unroll
            for (int j = 0; j < 2; ++j) {
                short8 bfr = *(const short8*)(wp + OFF_WE1 + (size_t)((s + 12) * 4 + cg * 2 + j) * 512 + lane * 8);
                acc[j] = __builtin_amdgcn_mfma_f32_32x32x16_bf16(a, bfr, acc[j], 0, 0, 0);
            }
        }
    }
    store32<2>(T1, acc, rg, colbase, r31, kh, true);    // Y1
    __syncthreads();   // B2: Y1 complete

    // ==== edge MLP layer 2 (K=128 spans both cg halves of Y1) ====
    gemm32_lds<8, 4, 2>(T1, wp + OFF_WE2, cg * 2, be2, acc, mrow, colbase, r31, kh, lane);
    __syncthreads();   // B2.5: all Y1 reads done before EF overwrites
    store32<2>(T1, acc, rg, colbase, r31, kh, true);    // EF
    __syncthreads();   // B3: EF complete

    // ==== coord MLP layer 1 (reads EF, all cols) ====
    gemm32_lds<8, 4, 2>(T1, wp + OFF_WC1, cg * 2, bc1, acc, mrow, colbase, r31, kh, lane);

    // ==== agg: segmented reduce over sorted rows (own rg rows, own cg cols) ====
    {
        const int col = colbase + lane;          // 64 cols per wave... cg*64 + lane&63
        const int m0 = rg * 32;
        int curr = rows_s[m0];
        float s = 0.f;
        for (int m = m0; m < m0 + 32; ++m) {
            int r = rows_s[m];
            float vv = b2f(*(const unsigned short*)((const char*)T1 + m * 256 + (((col & 127) * 2) ^ ((m & 7) << 4))));
            if (r != curr) { atomicAdd(&agg[(size_t)curr * HD + (col & 127)], s); s = 0.f; curr = r; }
            s += vv;
        }
        atomicAdd(&agg[(size_t)curr * HD + (col & 127)], s);
    }
    __syncthreads();   // B4: EF reads (C1 gemm + reduce) done
    store32<2>(T1, acc, rg, colbase, r31, kh, true);    // C1
    __syncthreads();   // B5: C1 complete

    // ==== coord final layer (cg=0 waves; N=22 fits one 32-col frag) + wind ====
    if (cg == 0) {
        gemm32_lds<8, 1, 1>(T1, wp + OFF_WCL, 0, (const float*)nullptr, acc, mrow, 0, r31, kh, lane);
        float* O22 = (float*)Twd;               // 64x32 f32 overlay (wd dead)
#pragma unroll
        for (int reg = 0; reg < 16; ++reg) {
            int row = rg * 32 + (reg & 3) + 8 * (reg >> 2) + 4 * kh;
            O22[row * 32 + r31] = acc[0][reg];
        }
        // wind segmented reduce: 16-row chains (rg, kh) over own-wave rows
        const int c = r31;
        if (c < 22) {
            const bool isU = c < LVN;
            const int lvl = isU ? c : c - LVN;
            float* dst = isU ? aggu : aggv;
            const float* radp = isU ? radu_s : radv_s;
            const int m0 = rg * 32 + kh * 16;
            int curr = rows_s[m0]; float s = 0.f;
            for (int m = m0; m < m0 + 16; ++m) {
                int r = rows_s[m];
                float vv = O22[m * 32 + c] * radp[m];
                if (r != curr) { atomicAdd(&dst[(size_t)curr * LVN + lvl], s); s = 0.f; curr = r; }
                s += vv;
            }
            atomicAdd(&dst[(size_t)curr * LVN + lvl], s);
        }
    }
}

// ================= post: lat-band mean | wind finalize =================
__global__ __launch_bounds__(256)
void post_kernel(const float* __restrict__ agg, short* __restrict__ latb,
                 float* __restrict__ aggu, float* __restrict__ aggv,
                 const int* __restrict__ off)
{
    const int b = blockIdx.x, tid = threadIdx.x;
    if (b < NLAT) {
        __shared__ float part[256];
        const int j = tid & 127, half = tid >> 7;
        float s = 0.f;
        for (int lon = half * 120; lon < (half + 1) * 120; ++lon)
            s += agg[((size_t)b * NLON + lon) * HD + j];
        part[tid] = s;
        __syncthreads();
        if (tid < 128)
            latb[(size_t)b * HD + tid] = f2b((part[tid] + part[128 + tid]) * (1.0f / NLON));
        return;
    }
    int tt = (b - NLAT) * 256 + tid;
    if (tt >= NN * LVN) return;
    int n = tt / LVN;
    float c = fmaxf((float)(off[n + 1] - off[n]), 1.f);
    float xu = aggu[tt] / c, xv = aggv[tt] / c;
    aggu[tt] = fminf(fmaxf(xu, -100.f), 100.f);
    aggv[tt] = fminf(fmaxf(xv, -100.f), 100.f);
}

// ================= node kernel: 128-node tiles, 8 waves, 32x32x16 =================
__global__ __launch_bounds__(512, 4)
void node_mfma(const short* __restrict__ hb, const float* __restrict__ h,
               const short* __restrict__ latb,
               const float* __restrict__ bn1, const float* __restrict__ bn2,
               const short* __restrict__ wp, float* __restrict__ out)
{
    __shared__ short T1[128 * 128];    // 32 KB
    const int tid = threadIdx.x, lane = tid & 63, w = tid >> 6;   // 8 waves
    const int rg = w >> 1, cg = w & 1;                             // rg 0..3
    const int r31 = lane & 31, kh = lane >> 5;
    const int mrow = rg * 32 + r31;                                // 0..127
    const int colbase = cg * 64;
    const int n0 = blockIdx.x * 128;
    const int n = n0 + mrow;
    const int nc = (n < NN) ? n : (NN - 1);
    const short* hp = hb + (size_t)nc * HD + 8 * kh;
    const float* ap = out + (size_t)nc * HD + 8 * kh;   // agg lives in out region
    const short* lp = latb + (size_t)(nc / NLON) * HD + 8 * kh;

    f16v acc[2];
#pragma unroll
    for (int j = 0; j < 2; ++j) {
        float bv = bn1[colbase + j * 32 + r31];
#pragma unroll
        for (int q = 0; q < 16; ++q) acc[j][q] = bv;
    }
    // h part (k 0..127)
#pragma unroll
    for (int s = 0; s < 8; ++s) {
        short8 a = *(const short8*)(hp + s * 16);
#pragma unroll
        for (int j = 0; j < 2; ++j) {
            short8 bfr = *(const short8*)(wp + OFF_WN1 + (size_t)(s * 4 + cg * 2 + j) * 512 + lane * 8);
            acc[j] = __builtin_amdgcn_mfma_f32_32x32x16_bf16(a, bfr, acc[j], 0, 0, 0);
        }
    }
    // agg part (k 128..255), f32 -> bf16 in reg
#pragma unroll
    for (int s = 0; s < 8; ++s) {
        short8 a;
#pragma unroll
        for (int q = 0; q < 8; ++q) a[q] = f2b(ap[s * 16 + q]);
#pragma unroll
        for (int j = 0; j < 2; ++j) {
            short8 bfr = *(const short8*)(wp + OFF_WN1 + (size_t)((s + 8) * 4 + cg * 2 + j) * 512 + lane * 8);
            acc[j] = __builtin_amdgcn_mfma_f32_32x32x16_bf16(a, bfr, acc[j], 0, 0, 0);
        }
    }
    // lat part (k 256..383)
#pragma unroll
    for (int s = 0; s < 8; ++s) {
        short8 a = *(const short8*)(lp + s * 16);
#pragma unroll
        for (int j = 0; j < 2; ++j) {
            short8 bfr = *(const short8*)(wp + OFF_WN1 + (size_t)((s + 16) * 4 + cg * 2 + j) * 512 + lane * 8);
            acc[j] = __builtin_amdgcn_mfma_f32_32x32x16_bf16(a, bfr, acc[j], 0, 0, 0);
        }
    }
    store32<2>(T1, acc, rg, colbase, r31, kh, true);
    __syncthreads();   // Wn2 K spans both cg halves
    gemm32_lds<8, 4, 2>(T1, wp + OFF_WN2, cg * 2, bn2, acc, mrow, colbase, r31, kh, lane);

    // out = acc + h (residual)
#pragma unroll
    for (int j = 0; j < 2; ++j)
#pragma unroll
        for (int reg = 0; reg < 16; ++reg) {
            int row = rg * 32 + (reg & 3) + 8 * (reg >> 2) + 4 * kh;
            int gn = n0 + row;
            if (gn < NN) {
                int col = colbase + j * 32 + r31;
                out[(size_t)gn * HD + col] = acc[j][reg] + h[(size_t)gn * HD + col];
            }
        }
}

extern "C" void kernel_launch(void* const* d_in, const int* in_sizes, int n_in,
                              void* d_out, int out_size, void* d_ws, size_t ws_size,
                              hipStream_t stream)
{
    const float* h   = (const float*)d_in[0];
    const float* u   = (const float*)d_in[1];
    const float* v   = (const float*)d_in[2];
    const float* ea  = (const float*)d_in[3];
    const float* We1 = (const float*)d_in[4];
    const float* be1 = (const float*)d_in[5];
    const float* We2 = (const float*)d_in[6];
    const float* be2 = (const float*)d_in[7];
    const float* Wn1 = (const float*)d_in[8];
    const float* bn1 = (const float*)d_in[9];
    const float* Wn2 = (const float*)d_in[10];
    const float* bn2 = (const float*)d_in[11];
    const float* Wc1 = (const float*)d_in[12];
    const float* bc1 = (const float*)d_in[13];
    const float* Wcl = (const float*)d_in[14];
    const int*   eidx = (const int*)d_in[15];

    float* out  = (float*)d_out;
    float* agg  = out;                       // [NN,HD]: agg accum, then h_out
    float* aggu = out + (size_t)NN * HD;
    float* aggv = aggu + (size_t)NN * LVN;

    // ---- workspace layout (no overlaps) ----
    char* p = (char*)d_ws;
    short* wp  = (short*)p;                  p += (size_t)WP_SHORTS * 2;
    int*   off = (int*)p;                    p += (size_t)(NN + 1) * 4;
    int*   csr = (int*)p;                    p += (size_t)EE * 4;
    p = (char*)(((size_t)p + 15) & ~(size_t)15);
    short* hb  = (short*)p;                  p += (size_t)NN * HD * 2;
    float* uvr = (float*)p;                  p += (size_t)NN * 36 * 4;
    short* latb = (short*)p;                 p += (size_t)NLAT * HD * 2;
    p = (char*)(((size_t)p + 15) & ~(size_t)15);
    int*   cnt = (int*)p;                    p += (size_t)NN * 4;
    int*   cur = (int*)p;

    hipMemsetAsync(d_out, 0, (size_t)out_size * sizeof(float), stream);
    hipMemsetAsync(cnt, 0, (size_t)2 * NN * sizeof(int), stream);

    setup_kernel<<<SB_HIST + SB_HCAST + SB_UV + SB_WP, 256, 0, stream>>>(
        eidx, cnt, h, hb, u, v, uvr, We1, We2, Wc1, Wcl, Wn1, Wn2, wp);
    scan_kernel<<<1, 1024, 0, stream>>>(cnt, off);
    scatter_kernel<<<EE / 256, 256, 0, stream>>>(eidx, off, cur, csr);

    edge_mfma<<<EE / 64, 256, 0, stream>>>(hb, uvr, ea, be1, be2, bc1,
                                           wp, eidx, csr, agg, aggu, aggv);

    post_kernel<<<NLAT + (NN * LVN + 255) / 256, 256, 0, stream>>>(
        agg, latb, aggu, aggv, off);

    node_mfma<<<(NN + 127) / 128, 512, 0, stream>>>(hb, h, latb, bn1, bn2, wp, agg);
}